// Round 8
// baseline (681.058 us; speedup 1.0000x reference)
//
#include <hip/hip_runtime.h>
#include <hip/hip_cooperative_groups.h>

// GridRNN B=4, S=T=128, H=256, D=3 — R13: revert to R11's step structure
// (R12's unroll caused scratch spills: +10MB FETCH/+19MB WRITE signature),
// and fuse all 4 phases into ONE cooperative kernel with grid.sync()
// (removes ~90us of inter-dispatch gaps measured in the R11 timeline).
//
// Phases (identical to R11 bodies):
//   P0: gemm0 (16 of 256 wgs): P0 = x0 @ Wih[0]^T + bias -> ws (1 MB)
//   P1: rnn2f<0>: h=tanh(P0 + h@Whh[0]^T); batched h x Wih[1] -> P1 -> out
//   P2: rnn2f<1>: h=tanh(P1 + h@Whh[1]^T); batched h x Wih[2] -> P2 -> out
//   P3: rnn2_last: h=tanh(P2 + h@Whh[2]^T); h -> out (spread store)
// grid.sync() + __threadfence() between phases (cross-wg P hand-off).
// Fallback 1: coop launch error -> R11's 4 sequential launches.
// Fallback 2: ws < 1MB -> v1 monolithic path.

#define SS 128
#define TT 128
#define HH 256
#define GRID_ELEMS ((size_t)4 * 128 * 128 * 256)

namespace cg = cooperative_groups;

typedef _Float16 half8 __attribute__((ext_vector_type(8)));
typedef float float4v __attribute__((ext_vector_type(4)));
typedef float float2v __attribute__((ext_vector_type(2)));

__device__ __forceinline__ float fast_tanh(float x) {
    float e = __expf(2.0f * x);
    return 1.0f - 2.0f / (e + 1.0f);
}

__device__ __forceinline__ unsigned short f2hbits(float x) {
    _Float16 h = (_Float16)x;
    return __builtin_bit_cast(unsigned short, h);
}

__device__ __forceinline__ float sel4(float4v v, int q) {
    float a = (q & 1) ? v[1] : v[0];
    float b = (q & 1) ? v[3] : v[2];
    return (q & 2) ? b : a;
}

__device__ __forceinline__ void lds_barrier() {
    asm volatile("s_waitcnt lgkmcnt(0)" ::: "memory");
    __builtin_amdgcn_s_barrier();
}

__device__ __forceinline__ half8 ldfrag_f32(const float* rowp, int k) {
    const float4v u0 = *(const float4v*)(rowp + k);
    const float4v u1 = *(const float4v*)(rowp + k + 4);
    half8 v;
#pragma unroll
    for (int e = 0; e < 4; ++e) { v[e] = (_Float16)u0[e]; v[4 + e] = (_Float16)u1[e]; }
    return v;
}

// ===================== phase body: gemm0 (compact P0 -> ws) =====================
__device__ __forceinline__ void gemm0_phase(
    const float* __restrict__ src, const float* __restrict__ trg,
    const float* __restrict__ Wx_ih, const float* __restrict__ Wy_ih,
    const float* __restrict__ bx_ih, const float* __restrict__ bx_hh,
    const float* __restrict__ by_ih, const float* __restrict__ by_hh,
    float* __restrict__ P0, int bx)
{
    __shared__ half8 aT[2048];   // 64 rows x 256 k (32 KB)

    const int tid  = threadIdx.x;
    const int lane = tid & 63;
    const int wv   = tid >> 6;
    const int quad = lane >> 4;
    const int l15  = lane & 15;

    const int dir   = bx >> 3;
    const int mtile = bx & 7;

    const float* Wih = dir ? Wy_ih : Wx_ih;   // depth 0
    const float* bih = dir ? by_ih : bx_ih;
    const float* bhh = dir ? by_hh : bx_hh;

    const int n_0 = (wv << 5) + l15;
    const int n_1 = n_0 + 16;

    half8 B0[8], B1[8];
    {
        const float* r0 = Wih + (size_t)n_0 * HH;
        const float* r1 = Wih + (size_t)n_1 * HH;
#pragma unroll
        for (int f = 0; f < 8; ++f) {
            const int k = (f << 5) + (quad << 3);
            B0[f] = ldfrag_f32(r0, k);
            B1[f] = ldfrag_f32(r1, k);
        }
    }
    const float bias0 = bih[n_0] + bhh[n_0];
    const float bias1 = bih[n_1] + bhh[n_1];

#pragma unroll
    for (int i = 0; i < 4; ++i) {
        const int c  = (tid << 2) + i;
        const int r  = c >> 5;
        const int kc = c & 31;
        const int R  = (mtile << 6) + r;
        const int b  = R >> 7, ii = R & 127;
        const float* row = (dir ? trg : src) + (size_t)((b << 7) + ii) * HH + (kc << 3);
        const float4v u0 = *(const float4v*)(row);
        const float4v u1 = *(const float4v*)(row + 4);
        half8 v;
#pragma unroll
        for (int e = 0; e < 4; ++e) { v[e] = (_Float16)u0[e]; v[4 + e] = (_Float16)u1[e]; }
        aT[((r >> 4) << 9) + ((kc >> 2) << 6) + ((kc & 3) << 4) + (r & 15)] = v;
    }
    __syncthreads();

#pragma unroll
    for (int msub = 0; msub < 4; ++msub) {
        half8 af[8];
#pragma unroll
        for (int f = 0; f < 8; ++f)
            af[f] = aT[(msub << 9) + (f << 6) + (quad << 4) + l15];

        float4v c0 = {bias0, bias0, bias0, bias0};
        float4v c1 = {bias1, bias1, bias1, bias1};
#pragma unroll
        for (int f = 0; f < 8; ++f) {
            c0 = __builtin_amdgcn_mfma_f32_16x16x32_f16(af[f], B0[f], c0, 0, 0, 0);
            c1 = __builtin_amdgcn_mfma_f32_16x16x32_f16(af[f], B1[f], c1, 0, 0, 0);
        }
#pragma unroll
        for (int r = 0; r < 4; ++r) {
            const int row = (msub << 4) + (quad << 2) + r;
            float* p = P0 + (size_t)dir * 131072 + (size_t)((mtile << 6) + row) * HH;
            p[n_0] = c0[r];
            p[n_1] = c1[r];
        }
    }
}

// ===================== phase body: fused recurrence (R11 structure) ==========
template <int DI>
__device__ __forceinline__ void rnn2f_phase(
    const float* __restrict__ Wx_hh, const float* __restrict__ Wy_hh,
    const float* __restrict__ Wx_ih, const float* __restrict__ Wy_ih,
    const float* __restrict__ bx_ih, const float* __restrict__ bx_hh,
    const float* __restrict__ by_ih, const float* __restrict__ by_hh,
    float* __restrict__ out, const float* __restrict__ P0, int bid)
{
    __shared__ half8 aH[8][128];   // ring: h(t) lives in aH[(t+1)&7], 16 KB

    const int tid  = threadIdx.x;
    const int lane = tid & 63;
    const int wv   = tid >> 6;
    const int quad = lane >> 4;
    const int l15  = lane & 15;
    const int lrow = lane & 3;

    const int isY  = bid >= 128;
    const int g0   = isY ? bid - 128 : bid;
    const int b    = g0 >> 5;
    const int c0   = (g0 & 31) << 2;
    const int slot = isY;

    const float* Whh  = (isY ? Wy_hh : Wx_hh) + (size_t)DI * HH * HH;
    const float* WihN = (isY ? Wy_ih : Wx_ih) + (size_t)(DI + 1) * HH * HH;
    const float* bihN = (isY ? by_ih : bx_ih) + (DI + 1) * HH;
    const float* bhhN = (isY ? by_hh : bx_hh) + (DI + 1) * HH;

    const int n_0 = (wv << 5) + l15;
    const int n_1 = n_0 + 16;

    half8 Bhh0[8], Bhh1[8], BN0[8], BN1[8];
    {
        const float* h0p = Whh  + (size_t)n_0 * HH;
        const float* h1p = Whh  + (size_t)n_1 * HH;
        const float* i0p = WihN + (size_t)n_0 * HH;
        const float* i1p = WihN + (size_t)n_1 * HH;
#pragma unroll
        for (int f = 0; f < 8; ++f) {
            const int k = (f << 5) + (quad << 3);
            Bhh0[f] = ldfrag_f32(h0p, k);
            Bhh1[f] = ldfrag_f32(h1p, k);
            BN0[f]  = ldfrag_f32(i0p, k);
            BN1[f]  = ldfrag_f32(i1p, k);
        }
    }
    const float biasN0 = bihN[n_0] + bhhN[n_0];
    const float biasN1 = bihN[n_1] + bhhN[n_1];

    // ---- P read FIFO (2 scalars/step, 4-deep)
    float pA[4], pB[4];
    int rj = isY ? 0 : ((c0 + quad) & 127);
    const float* rp;
    if constexpr (DI == 0) {
        rp = P0 + (size_t)isY * 131072 + (size_t)b * 128 * HH;
    } else {
        rp = out + (isY ? ((size_t)(b * SS + c0 + quad) * TT)
                        : ((size_t)b * SS * TT + rj)) * 2 * HH
                 + (size_t)slot * HH;
    }
    auto rbump = [&]() {
        if constexpr (DI == 0) { rp += HH; }
        else if (isY)          { rp += 2 * HH; }
        else { rp += (size_t)(rj == 127 ? 1 : 129) * 2 * HH; rj = (rj + 1) & 127; }
    };
#pragma unroll
    for (int u = 0; u < 4; ++u) { pA[u] = rp[n_0]; pB[u] = rp[n_1]; rbump(); }

    // ---- P_next store: group first-cell t4; lane quad = step, reg r = chain
    auto store_group = [&](int t4, const float4v& v0, const float4v& v1) {
        const int t = t4 + quad;
#pragma unroll
        for (int r = 0; r < 4; ++r) {
            const int ch = c0 + r;
            const size_t cell = isY ? ((size_t)(b * SS + ch) * TT + t)
                                    : ((size_t)(b * SS + t) * TT + ((ch + t) & 127));
            float* p = out + cell * 2 * HH + (size_t)slot * HH;
            p[n_0] = v0[r];
            p[n_1] = v1[r];
        }
    };

    if (tid < 128) {
        half8 z;
#pragma unroll
        for (int e = 0; e < 8; ++e) z[e] = (_Float16)0.f;
        aH[0][tid] = z;   // h(-1) = 0
    }
    __syncthreads();

    const int hi  = l15 >> 3;
    const int lo3 = l15 & 7;

    float4v pn0 = {0.f, 0.f, 0.f, 0.f}, pn1 = {0.f, 0.f, 0.f, 0.f};
    float4v st0 = {0.f, 0.f, 0.f, 0.f}, st1 = {0.f, 0.f, 0.f, 0.f};

    for (int g = 0; g < 32; ++g) {
#pragma unroll
        for (int u = 0; u < 4; ++u) {
            const int s = (g << 2) + u;

            // ---- post-barrier: deferred store of group g-2 ----
            if (u == 0 && g >= 2) store_group(((g - 2) << 2), st0, st1);

            // FIFO: consume P(s), refill slot u with P(s+4)
            const float pAu = pA[u], pBu = pB[u];
            if (s + 4 < 128) { pA[u] = rp[n_0]; pB[u] = rp[n_1]; rbump(); }

            // hh frags: h(s-1) from aH[s&7]; rows mirror mod 4
            const half8* hb = aH[s & 7];
            half8 ahr[8];
#pragma unroll
            for (int f = 0; f < 8; ++f)
                ahr[f] = hb[(f << 4) + (quad << 2) + lrow];

            // hh MFMAs, K split into 2 halves (4-deep dep chains)
            float4v a0a = {0.f,0.f,0.f,0.f}, a0b = {0.f,0.f,0.f,0.f};
            float4v a1a = {0.f,0.f,0.f,0.f}, a1b = {0.f,0.f,0.f,0.f};
            __builtin_amdgcn_s_setprio(1);
#pragma unroll
            for (int f = 0; f < 4; ++f) {
                a0a = __builtin_amdgcn_mfma_f32_16x16x32_f16(ahr[f],     Bhh0[f],     a0a, 0, 0, 0);
                a1a = __builtin_amdgcn_mfma_f32_16x16x32_f16(ahr[f],     Bhh1[f],     a1a, 0, 0, 0);
                a0b = __builtin_amdgcn_mfma_f32_16x16x32_f16(ahr[f + 4], Bhh0[f + 4], a0b, 0, 0, 0);
                a1b = __builtin_amdgcn_mfma_f32_16x16x32_f16(ahr[f + 4], Bhh1[f + 4], a1b, 0, 0, 0);
            }
            __builtin_amdgcn_s_setprio(0);

            // h(s) = tanh(hh + P(s)); scatter into aH[(s+1)&7]
            const float h0 = fast_tanh(sel4(a0a, quad) + sel4(a0b, quad) + pAu);
            const float h1 = fast_tanh(sel4(a1a, quad) + sel4(a1b, quad) + pBu);
            unsigned short* aHu = (unsigned short*)aH[(s + 1) & 7];
            aHu[(((wv << 4) + (hi << 2) + quad) << 3) + lo3]       = f2hbits(h0);
            aHu[(((wv << 4) + ((2 + hi) << 2) + quad) << 3) + lo3] = f2hbits(h1);

            __builtin_amdgcn_sched_barrier(0);

            // ---- batched ih for group g-1: 2 frag reads + 4 MFMA ----
            if (g >= 1) {
                if (u == 0) {
                    pn0 = float4v{biasN0, biasN0, biasN0, biasN0};
                    pn1 = float4v{biasN1, biasN1, biasN1, biasN1};
                }
                const half8* ib = aH[((g << 2) - 3 + (l15 >> 2)) & 7];
#pragma unroll
                for (int ff = 0; ff < 2; ++ff) {
                    const int f = (u << 1) + ff;
                    const half8 af = ib[(f << 4) + (quad << 2) + (l15 & 3)];
                    pn0 = __builtin_amdgcn_mfma_f32_16x16x32_f16(af, BN0[f], pn0, 0, 0, 0);
                    pn1 = __builtin_amdgcn_mfma_f32_16x16x32_f16(af, BN1[f], pn1, 0, 0, 0);
                }
                if (u == 3) { st0 = pn0; st1 = pn1; }
            }

            lds_barrier();                       // LDS-only: no vmcnt drain
            __builtin_amdgcn_sched_barrier(0);
        }
    }

    // epilogue: store group 30 (carried), compute+store group 31
    store_group((30 << 2), st0, st1);
    {
        float4v p0 = {biasN0, biasN0, biasN0, biasN0};
        float4v p1 = {biasN1, biasN1, biasN1, biasN1};
        const half8* ib = aH[(5 + (l15 >> 2)) & 7];   // h(124..127) -> bufs 5,6,7,0
#pragma unroll
        for (int f = 0; f < 8; ++f) {
            const half8 af = ib[(f << 4) + (quad << 2) + (l15 & 3)];
            p0 = __builtin_amdgcn_mfma_f32_16x16x32_f16(af, BN0[f], p0, 0, 0, 0);
            p1 = __builtin_amdgcn_mfma_f32_16x16x32_f16(af, BN1[f], p1, 0, 0, 0);
        }
        store_group((31 << 2), p0, p1);
    }
}

// ===================== phase body: final depth (d=2) =====================
__device__ __forceinline__ void rnn2_last_phase(
    const float* __restrict__ Wx_hh, const float* __restrict__ Wy_hh,
    float* __restrict__ out, int bid)
{
    __shared__ half8 aH[2][128];

    const int tid  = threadIdx.x;
    const int lane = tid & 63;
    const int wv   = tid >> 6;
    const int quad = lane >> 4;
    const int l15  = lane & 15;
    const int lrow = lane & 3;

    const int isY  = bid >= 128;
    const int g    = isY ? bid - 128 : bid;
    const int b    = g >> 5;
    const int c0   = (g & 31) << 2;
    const int slot = isY;

    const float* Whh = (isY ? Wy_hh : Wx_hh) + (size_t)2 * HH * HH;

    const int n_0 = (wv << 5) + l15;
    const int n_1 = n_0 + 16;

    half8 Bhh0[8], Bhh1[8];
    {
        const float* r0 = Whh + (size_t)n_0 * HH;
        const float* r1 = Whh + (size_t)n_1 * HH;
#pragma unroll
        for (int f = 0; f < 8; ++f) {
            const int k = (f << 5) + (quad << 3);
            Bhh0[f] = ldfrag_f32(r0, k);
            Bhh1[f] = ldfrag_f32(r1, k);
        }
    }

    // ---- P read FIFO (chain = quad, 4-deep)
    float pA[4], pB[4];
    int rj = isY ? 0 : ((c0 + quad) & 127);
    const float* rp = out + (isY ? ((size_t)(b * SS + c0 + quad) * TT)
                                 : ((size_t)b * SS * TT + rj)) * 2 * HH
                          + (size_t)slot * HH;
    auto rbump = [&]() {
        if (isY) { rp += 2 * HH; }
        else { rp += (size_t)(rj == 127 ? 1 : 129) * 2 * HH; rj = (rj + 1) & 127; }
    };
#pragma unroll
    for (int u = 0; u < 4; ++u) { pA[u] = rp[n_0]; pB[u] = rp[n_1]; rbump(); }

    // ---- spread h-store: thread handles chain sm=tid>>7, floats kk,kk+1
    const int sm = tid >> 7;
    const int kk = (tid & 127) << 1;
    int sj = isY ? 0 : ((c0 + sm) & 127);
    float* sp = out + (isY ? ((size_t)(b * SS + c0 + sm) * TT)
                           : ((size_t)b * SS * TT + sj)) * 2 * HH
                    + (size_t)slot * HH + kk;
    const int rb32 = ((((kk >> 3) << 2) + sm) << 3 | (kk & 7)) >> 1;  // u32 idx in aH buf

    auto store_spread = [&](int bufi) {
        const unsigned int* a32 = (const unsigned int*)aH[bufi];
        const unsigned int w = a32[rb32];
        const _Float16 lo = __builtin_bit_cast(_Float16, (unsigned short)(w & 0xffff));
        const _Float16 hv = __builtin_bit_cast(_Float16, (unsigned short)(w >> 16));
        float2v t; t[0] = (float)lo; t[1] = (float)hv;
        *(float2v*)sp = t;
        if (isY) { sp += 2 * HH; }
        else { sp += (size_t)(sj == 127 ? 1 : 129) * 2 * HH; sj = (sj + 1) & 127; }
    };

    if (tid < 128) {
        half8 z;
#pragma unroll
        for (int e = 0; e < 8; ++e) z[e] = (_Float16)0.f;
        aH[0][tid] = z;
    }
    __syncthreads();

    const int hi  = l15 >> 3;
    const int lo3 = l15 & 7;

    int buf = 0;
    for (int s4 = 0; s4 < 128; s4 += 4) {
#pragma unroll
        for (int u = 0; u < 4; ++u) {
            const int s = s4 + u;

            if (s > 0) store_spread(buf);   // h(s-1) -> out (overwrites consumed P)

            const float pAu = pA[u], pBu = pB[u];
            if (s + 4 < 128) { pA[u] = rp[n_0]; pB[u] = rp[n_1]; rbump(); }

            half8 ahr[8];
#pragma unroll
            for (int f = 0; f < 8; ++f)
                ahr[f] = aH[buf][(f << 4) + (quad << 2) + lrow];

            float4v a0a = {0.f,0.f,0.f,0.f}, a0b = {0.f,0.f,0.f,0.f};
            float4v a1a = {0.f,0.f,0.f,0.f}, a1b = {0.f,0.f,0.f,0.f};
            __builtin_amdgcn_s_setprio(1);
#pragma unroll
            for (int f = 0; f < 4; ++f) {
                a0a = __builtin_amdgcn_mfma_f32_16x16x32_f16(ahr[f],     Bhh0[f],     a0a, 0, 0, 0);
                a1a = __builtin_amdgcn_mfma_f32_16x16x32_f16(ahr[f],     Bhh1[f],     a1a, 0, 0, 0);
                a0b = __builtin_amdgcn_mfma_f32_16x16x32_f16(ahr[f + 4], Bhh0[f + 4], a0b, 0, 0, 0);
                a1b = __builtin_amdgcn_mfma_f32_16x16x32_f16(ahr[f + 4], Bhh1[f + 4], a1b, 0, 0, 0);
            }
            __builtin_amdgcn_s_setprio(0);

            const float h0 = fast_tanh(sel4(a0a, quad) + sel4(a0b, quad) + pAu);
            const float h1 = fast_tanh(sel4(a1a, quad) + sel4(a1b, quad) + pBu);
            unsigned short* aHu = (unsigned short*)aH[buf ^ 1];
            aHu[(((wv << 4) + (hi << 2) + quad) << 3) + lo3]       = f2hbits(h0);
            aHu[(((wv << 4) + ((2 + hi) << 2) + quad) << 3) + lo3] = f2hbits(h1);

            lds_barrier();
            __builtin_amdgcn_sched_barrier(0);
            buf ^= 1;
        }
    }

    store_spread(buf);   // h(127)
}

// ===================== fused cooperative kernel =====================
extern "C" __global__ void __launch_bounds__(512, 1)
grnn_all(const float* __restrict__ src, const float* __restrict__ trg,
         const float* __restrict__ Wx_ih, const float* __restrict__ Wx_hh,
         const float* __restrict__ bx_ih, const float* __restrict__ bx_hh,
         const float* __restrict__ Wy_ih, const float* __restrict__ Wy_hh,
         const float* __restrict__ by_ih, const float* __restrict__ by_hh,
         float* __restrict__ out, float* __restrict__ P0)
{
    const int bid = blockIdx.x;
    cg::grid_group grid = cg::this_grid();

    if (bid < 16)
        gemm0_phase(src, trg, Wx_ih, Wy_ih, bx_ih, bx_hh, by_ih, by_hh, P0, bid);
    __threadfence();
    grid.sync();

    rnn2f_phase<0>(Wx_hh, Wy_hh, Wx_ih, Wy_ih, bx_ih, bx_hh, by_ih, by_hh,
                   out, P0, bid);
    __threadfence();
    grid.sync();

    rnn2f_phase<1>(Wx_hh, Wy_hh, Wx_ih, Wy_ih, bx_ih, bx_hh, by_ih, by_hh,
                   out, P0, bid);
    __threadfence();
    grid.sync();

    rnn2_last_phase(Wx_hh, Wy_hh, out, bid);
}

// ===================== separate kernels (fallback if coop launch fails) =====
extern "C" __global__ void __launch_bounds__(512, 2)
grid_gemm0(const float* __restrict__ src, const float* __restrict__ trg,
           const float* __restrict__ Wx_ih, const float* __restrict__ Wy_ih,
           const float* __restrict__ bx_ih, const float* __restrict__ bx_hh,
           const float* __restrict__ by_ih, const float* __restrict__ by_hh,
           float* __restrict__ P0)
{ gemm0_phase(src, trg, Wx_ih, Wy_ih, bx_ih, bx_hh, by_ih, by_hh, P0, blockIdx.x); }

extern "C" __global__ void __launch_bounds__(512, 1)
grid_rnn2f_d0(const float* __restrict__ Wx_hh, const float* __restrict__ Wy_hh,
              const float* __restrict__ Wx_ih, const float* __restrict__ Wy_ih,
              const float* __restrict__ bx_ih, const float* __restrict__ bx_hh,
              const float* __restrict__ by_ih, const float* __restrict__ by_hh,
              float* __restrict__ out, const float* __restrict__ P0)
{ rnn2f_phase<0>(Wx_hh, Wy_hh, Wx_ih, Wy_ih, bx_ih, bx_hh, by_ih, by_hh, out, P0, blockIdx.x); }

extern "C" __global__ void __launch_bounds__(512, 1)
grid_rnn2f_d1(const float* __restrict__ Wx_hh, const float* __restrict__ Wy_hh,
              const float* __restrict__ Wx_ih, const float* __restrict__ Wy_ih,
              const float* __restrict__ bx_ih, const float* __restrict__ bx_hh,
              const float* __restrict__ by_ih, const float* __restrict__ by_hh,
              float* __restrict__ out, const float* __restrict__ P0)
{ rnn2f_phase<1>(Wx_hh, Wy_hh, Wx_ih, Wy_ih, bx_ih, bx_hh, by_ih, by_hh, out, P0, blockIdx.x); }

extern "C" __global__ void __launch_bounds__(512, 2)
grid_rnn2_last(const float* __restrict__ Wx_hh, const float* __restrict__ Wy_hh,
               float* __restrict__ out)
{ rnn2_last_phase(Wx_hh, Wy_hh, out, blockIdx.x); }

// ===================== fallback (tiny ws): v1 monolithic path ===============
template <int DI>
__device__ __forceinline__ void grid_rnn_body_v1(
    const float* __restrict__ src, const float* __restrict__ trg,
    const float* __restrict__ Wx_ih, const float* __restrict__ Wx_hh,
    const float* __restrict__ bx_ih, const float* __restrict__ bx_hh,
    const float* __restrict__ Wy_ih, const float* __restrict__ Wy_hh,
    const float* __restrict__ by_ih, const float* __restrict__ by_hh,
    float* __restrict__ out)
{
    __shared__ half8 aX[2][128];
    __shared__ half8 aH[2][128];

    const int tid  = threadIdx.x;
    const int lane = tid & 63;
    const int wv   = tid >> 6;
    const int quad = lane >> 4;
    const int l15  = lane & 15;

    const int bid  = blockIdx.x;
    const int isY  = bid >= 128;
    const int g    = isY ? bid - 128 : bid;
    const int b    = g >> 5;
    const int c0   = (g & 31) << 2;
    const int slot = isY;

    const float* Wih = (isY ? Wy_ih : Wx_ih) + (size_t)DI * HH * HH;
    const float* Whh = (isY ? Wy_hh : Wx_hh) + (size_t)DI * HH * HH;
    const float* bih = (isY ? by_ih : bx_ih) + DI * HH;
    const float* bhh = (isY ? by_hh : bx_hh) + DI * HH;

    const int n_0 = (wv << 5) + l15;
    const int n_1 = n_0 + 16;

    half8 Bih0[8], Bih1[8], Bhh0[8], Bhh1[8];
    {
        const float* r0i = Wih + (size_t)n_0 * HH;
        const float* r1i = Wih + (size_t)n_1 * HH;
        const float* r0h = Whh + (size_t)n_0 * HH;
        const float* r1h = Whh + (size_t)n_1 * HH;
#pragma unroll
        for (int f = 0; f < 8; ++f) {
            const int k = (f << 5) + (quad << 3);
            Bih0[f] = ldfrag_f32(r0i, k);
            Bih1[f] = ldfrag_f32(r1i, k);
            Bhh0[f] = ldfrag_f32(r0h, k);
            Bhh1[f] = ldfrag_f32(r1h, k);
        }
    }
    const float bias0 = bih[n_0] + bhh[n_0];
    const float bias1 = bih[n_1] + bhh[n_1];

    const int sact = (tid < 128);
    const int cm   = tid & 3;
    const int ck0  = (tid >> 2) << 3;
    const int chc  = c0 + cm;

    auto stage_now = [&](int sn) -> half8 {
        const int i = isY ? chc : sn;
        const int j = isY ? sn : ((chc + sn) & 127);
        const size_t cell = (size_t)(b * SS + i) * TT + j;
        half8 v;
        if constexpr (DI == 0) {
            const float* row = isY ? (trg + (size_t)(b * TT + j) * HH)
                                   : (src + (size_t)(b * SS + i) * HH);
            const float4v u0 = *(const float4v*)(row + ck0);
            const float4v u1 = *(const float4v*)(row + ck0 + 4);
#pragma unroll
            for (int e = 0; e < 4; ++e) { v[e] = (_Float16)u0[e]; v[4 + e] = (_Float16)u1[e]; }
        } else {
            const float* row = out + cell * 2 * HH + (size_t)slot * HH + ck0;
            const float4v u0 = *(const float4v*)(row);
            const float4v u1 = *(const float4v*)(row + 4);
#pragma unroll
            for (int e = 0; e < 4; ++e) { v[e] = (_Float16)u0[e]; v[4 + e] = (_Float16)u1[e]; }
        }
        return v;
    };

    auto store_h = [&](int sp, int bufi) {
        const half8 v = aH[bufi][tid];
        const int i = isY ? chc : sp;
        const int j = isY ? sp : ((chc + sp) & 127);
        const size_t cell = (size_t)(b * SS + i) * TT + j;
        float* p = out + cell * 2 * HH + (size_t)slot * HH + ck0;
        float4v u0, u1;
#pragma unroll
        for (int e = 0; e < 4; ++e) { u0[e] = (float)v[e]; u1[e] = (float)v[4 + e]; }
        *(float4v*)p = u0;
        *(float4v*)(p + 4) = u1;
    };

    if (sact) {
        half8 z;
#pragma unroll
        for (int e = 0; e < 8; ++e) z[e] = (_Float16)0.f;
        aH[0][tid] = z;
        aX[0][tid] = stage_now(0);
    }
    __syncthreads();

    const int lrow = lane & 3;

    int buf = 0;
    for (int s = 0; s < 128; ++s) {
        if (s > 0 && sact) store_h(s - 1, buf);
        if (sact) {
            int t = s + 1; if (t > 127) t = 127;
            aX[buf ^ 1][tid] = stage_now(t);
        }

        half8 axr[8], ahr[8];
#pragma unroll
        for (int f = 0; f < 8; ++f) {
            const int e = (f << 4) + (quad << 2) + lrow;
            axr[f] = aX[buf][e];
            ahr[f] = aH[buf][e];
        }

        float4v ax0 = {bias0, bias0, bias0, bias0};
        float4v ax1 = {bias1, bias1, bias1, bias1};
        float4v ah0 = {0.f, 0.f, 0.f, 0.f};
        float4v ah1 = {0.f, 0.f, 0.f, 0.f};
#pragma unroll
        for (int f = 0; f < 8; ++f) {
            ax0 = __builtin_amdgcn_mfma_f32_16x16x32_f16(axr[f], Bih0[f], ax0, 0, 0, 0);
            ax1 = __builtin_amdgcn_mfma_f32_16x16x32_f16(axr[f], Bih1[f], ax1, 0, 0, 0);
            ah0 = __builtin_amdgcn_mfma_f32_16x16x32_f16(ahr[f], Bhh0[f], ah0, 0, 0, 0);
            ah1 = __builtin_amdgcn_mfma_f32_16x16x32_f16(ahr[f], Bhh1[f], ah1, 0, 0, 0);
        }

        if (quad == 0) {
            unsigned short* aHu = (unsigned short*)aH[buf ^ 1];
            const int lo3 = lane & 7;
            const int hi  = lane >> 3;
#pragma unroll
            for (int r = 0; r < 4; ++r) {
                const float h0 = fast_tanh(ax0[r] + ah0[r]);
                const float h1 = fast_tanh(ax1[r] + ah1[r]);
                aHu[(wv << 7) + (hi << 5) + (r << 3) + lo3]       = f2hbits(h0);
                aHu[(wv << 7) + ((2 + hi) << 5) + (r << 3) + lo3] = f2hbits(h1);
            }
        }

        lds_barrier();
        buf ^= 1;
    }

    if (sact) store_h(127, buf);
}

extern "C" __global__ void __launch_bounds__(512, 2)
grid_rnn_v1_d0(const float* __restrict__ src, const float* __restrict__ trg,
               const float* __restrict__ Wx_ih, const float* __restrict__ Wx_hh,
               const float* __restrict__ bx_ih, const float* __restrict__ bx_hh,
               const float* __restrict__ Wy_ih, const float* __restrict__ Wy_hh,
               const float* __restrict__ by_ih, const float* __restrict__ by_hh,
               float* __restrict__ out)
{ grid_rnn_body_v1<0>(src, trg, Wx_ih, Wx_hh, bx_ih, bx_hh, Wy_ih, Wy_hh, by_ih, by_hh, out); }

extern "C" __global__ void __launch_bounds__(512, 2)
grid_rnn_v1_d1(const float* __restrict__ src, const float* __restrict__ trg,
               const float* __restrict__ Wx_ih, const float* __restrict__ Wx_hh,
               const float* __restrict__ bx_ih, const float* __restrict__ bx_hh,
               const float* __restrict__ Wy_ih, const float* __restrict__ Wy_hh,
               const float* __restrict__ by_ih, const float* __restrict__ by_hh,
               float* __restrict__ out)
{ grid_rnn_body_v1<1>(src, trg, Wx_ih, Wx_hh, bx_ih, bx_hh, Wy_ih, Wy_hh, by_ih, by_hh, out); }

extern "C" __global__ void __launch_bounds__(512, 2)
grid_rnn_v1_d2(const float* __restrict__ src, const float* __restrict__ trg,
               const float* __restrict__ Wx_ih, const float* __restrict__ Wx_hh,
               const float* __restrict__ bx_ih, const float* __restrict__ bx_hh,
               const float* __restrict__ Wy_ih, const float* __restrict__ Wy_hh,
               const float* __restrict__ by_ih, const float* __restrict__ by_hh,
               float* __restrict__ out)
{ grid_rnn_body_v1<2>(src, trg, Wx_ih, Wx_hh, bx_ih, bx_hh, Wy_ih, Wy_hh, by_ih, by_hh, out); }

// ===================== launch =====================
extern "C" void kernel_launch(void* const* d_in, const int* in_sizes, int n_in,
                              void* d_out, int out_size, void* d_ws, size_t ws_size,
                              hipStream_t stream) {
    const float* src   = (const float*)d_in[0];
    const float* trg   = (const float*)d_in[1];
    const float* Wx_ih = (const float*)d_in[2];
    const float* Wx_hh = (const float*)d_in[3];
    const float* bx_ih = (const float*)d_in[4];
    const float* bx_hh = (const float*)d_in[5];
    const float* Wy_ih = (const float*)d_in[6];
    const float* Wy_hh = (const float*)d_in[7];
    const float* by_ih = (const float*)d_in[8];
    const float* by_hh = (const float*)d_in[9];
    float* out = (float*)d_out;
    float* wsf = (float*)d_ws;

    const size_t needP0 = (size_t)2 * 131072 * sizeof(float);  // 1 MB

    if (ws_size >= needP0) {
        void* args[] = {
            (void*)&src, (void*)&trg,
            (void*)&Wx_ih, (void*)&Wx_hh, (void*)&bx_ih, (void*)&bx_hh,
            (void*)&Wy_ih, (void*)&Wy_hh, (void*)&by_ih, (void*)&by_hh,
            (void*)&out, (void*)&wsf
        };
        hipError_t err = hipLaunchCooperativeKernel(
            (void*)grnn_all, dim3(256), dim3(512), args, 0, stream);
        if (err != hipSuccess) {
            // fallback: R11's proven 4-launch sequence
            hipLaunchKernelGGL(grid_gemm0, dim3(16), dim3(512), 0, stream,
                               src, trg, Wx_ih, Wy_ih, bx_ih, bx_hh, by_ih, by_hh, wsf);
            hipLaunchKernelGGL(grid_rnn2f_d0, dim3(256), dim3(512), 0, stream,
                               Wx_hh, Wy_hh, Wx_ih, Wy_ih, bx_ih, bx_hh, by_ih, by_hh,
                               out, (const float*)wsf);
            hipLaunchKernelGGL(grid_rnn2f_d1, dim3(256), dim3(512), 0, stream,
                               Wx_hh, Wy_hh, Wx_ih, Wy_ih, bx_ih, bx_hh, by_ih, by_hh,
                               out, (const float*)wsf);
            hipLaunchKernelGGL(grid_rnn2_last, dim3(256), dim3(512), 0, stream,
                               Wx_hh, Wy_hh, out);
        }
    } else {
        hipLaunchKernelGGL(grid_rnn_v1_d0, dim3(256), dim3(512), 0, stream,
                           src, trg, Wx_ih, Wx_hh, bx_ih, bx_hh,
                           Wy_ih, Wy_hh, by_ih, by_hh, out);
        hipLaunchKernelGGL(grid_rnn_v1_d1, dim3(256), dim3(512), 0, stream,
                           src, trg, Wx_ih, Wx_hh, bx_ih, bx_hh,
                           Wy_ih, Wy_hh, by_ih, by_hh, out);
        hipLaunchKernelGGL(grid_rnn_v1_d2, dim3(256), dim3(512), 0, stream,
                           src, trg, Wx_ih, Wx_hh, bx_ih, bx_hh,
                           Wy_ih, Wy_hh, by_ih, by_hh, out);
    }
}

// Round 9
// 442.730 us; speedup vs baseline: 1.5383x; 1.5383x over previous
//
#include <hip/hip_runtime.h>

// GridRNN B=4, S=T=128, H=256, D=3 — R14: revert to R11 (best, 418us) +
// hoist ih A-frag reads to the top of the step (R12's intent WITHOUT the
// 8-slot unroll that caused scratch spills).
//
// R13 lesson: cooperative grid.sync costs ~80us each on MI355X — fusion
// abandoned. 4-launch structure restored.
//
// Pipeline (ws >= 1MB path; ws holds compact P0, f32, 1 MB):
//   gemm0      : P0[dir][b*128+t][n] = x0 @ Wih[0]^T + bih0+bhh0 -> ws
//   rnn2f<0>   : h=tanh(P0 + h@Whh[0]^T); batched h x Wih[1] -> P1 -> out
//   rnn2f<1>   : h=tanh(P1 + h@Whh[1]^T); batched h x Wih[2] -> P2 -> out
//   rnn2_last  : h=tanh(P2 + h@Whh[2]^T); h -> out f32 (spread store)
//
// rnn2f step: [barrier] -> issue 2 ih reads + 8 hh reads -> {store|FIFO}
//   -> 16 hh MFMA (setprio1) -> tanh -> scatter -> [sched_barrier]
//   -> 4 ih MFMA (operands long since arrived) -> lds_barrier.

#define SS 128
#define TT 128
#define HH 256
#define GRID_ELEMS ((size_t)4 * 128 * 128 * 256)

typedef _Float16 half8 __attribute__((ext_vector_type(8)));
typedef float float4v __attribute__((ext_vector_type(4)));
typedef float float2v __attribute__((ext_vector_type(2)));

__device__ __forceinline__ float fast_tanh(float x) {
    float e = __expf(2.0f * x);
    return 1.0f - 2.0f / (e + 1.0f);
}

__device__ __forceinline__ unsigned short f2hbits(float x) {
    _Float16 h = (_Float16)x;
    return __builtin_bit_cast(unsigned short, h);
}

__device__ __forceinline__ float sel4(float4v v, int q) {
    float a = (q & 1) ? v[1] : v[0];
    float b = (q & 1) ? v[3] : v[2];
    return (q & 2) ? b : a;
}

__device__ __forceinline__ void lds_barrier() {
    asm volatile("s_waitcnt lgkmcnt(0)" ::: "memory");
    __builtin_amdgcn_s_barrier();
}

__device__ __forceinline__ half8 ldfrag_f32(const float* rowp, int k) {
    const float4v u0 = *(const float4v*)(rowp + k);
    const float4v u1 = *(const float4v*)(rowp + k + 4);
    half8 v;
#pragma unroll
    for (int e = 0; e < 4; ++e) { v[e] = (_Float16)u0[e]; v[4 + e] = (_Float16)u1[e]; }
    return v;
}

// ===================== gemm0: compact P0 -> ws =====================
extern "C" __global__ void __launch_bounds__(512, 2)
grid_gemm0(const float* __restrict__ src, const float* __restrict__ trg,
           const float* __restrict__ Wx_ih, const float* __restrict__ Wy_ih,
           const float* __restrict__ bx_ih, const float* __restrict__ bx_hh,
           const float* __restrict__ by_ih, const float* __restrict__ by_hh,
           float* __restrict__ P0)
{
    __shared__ half8 aT[2048];   // 64 rows x 256 k

    const int tid  = threadIdx.x;
    const int lane = tid & 63;
    const int wv   = tid >> 6;
    const int quad = lane >> 4;
    const int l15  = lane & 15;

    const int bx    = blockIdx.x;   // 0..15
    const int dir   = bx >> 3;
    const int mtile = bx & 7;

    const float* Wih = dir ? Wy_ih : Wx_ih;   // depth 0
    const float* bih = dir ? by_ih : bx_ih;
    const float* bhh = dir ? by_hh : bx_hh;

    const int n_0 = (wv << 5) + l15;
    const int n_1 = n_0 + 16;

    half8 B0[8], B1[8];
    {
        const float* r0 = Wih + (size_t)n_0 * HH;
        const float* r1 = Wih + (size_t)n_1 * HH;
#pragma unroll
        for (int f = 0; f < 8; ++f) {
            const int k = (f << 5) + (quad << 3);
            B0[f] = ldfrag_f32(r0, k);
            B1[f] = ldfrag_f32(r1, k);
        }
    }
    const float bias0 = bih[n_0] + bhh[n_0];
    const float bias1 = bih[n_1] + bhh[n_1];

#pragma unroll
    for (int i = 0; i < 4; ++i) {
        const int c  = (tid << 2) + i;
        const int r  = c >> 5;
        const int kc = c & 31;
        const int R  = (mtile << 6) + r;
        const int b  = R >> 7, ii = R & 127;
        const float* row = (dir ? trg : src) + (size_t)((b << 7) + ii) * HH + (kc << 3);
        const float4v u0 = *(const float4v*)(row);
        const float4v u1 = *(const float4v*)(row + 4);
        half8 v;
#pragma unroll
        for (int e = 0; e < 4; ++e) { v[e] = (_Float16)u0[e]; v[4 + e] = (_Float16)u1[e]; }
        aT[((r >> 4) << 9) + ((kc >> 2) << 6) + ((kc & 3) << 4) + (r & 15)] = v;
    }
    __syncthreads();

#pragma unroll
    for (int msub = 0; msub < 4; ++msub) {
        half8 af[8];
#pragma unroll
        for (int f = 0; f < 8; ++f)
            af[f] = aT[(msub << 9) + (f << 6) + (quad << 4) + l15];

        float4v c0 = {bias0, bias0, bias0, bias0};
        float4v c1 = {bias1, bias1, bias1, bias1};
#pragma unroll
        for (int f = 0; f < 8; ++f) {
            c0 = __builtin_amdgcn_mfma_f32_16x16x32_f16(af[f], B0[f], c0, 0, 0, 0);
            c1 = __builtin_amdgcn_mfma_f32_16x16x32_f16(af[f], B1[f], c1, 0, 0, 0);
        }
#pragma unroll
        for (int r = 0; r < 4; ++r) {
            const int row = (msub << 4) + (quad << 2) + r;
            float* p = P0 + (size_t)dir * 131072 + (size_t)((mtile << 6) + row) * HH;
            p[n_0] = c0[r];
            p[n_1] = c1[r];
        }
    }
}

// ===================== fused recurrence (depths 0,1) =====================
template <int DI>
__device__ __forceinline__ void rnn2f_body(
    const float* __restrict__ Wx_hh, const float* __restrict__ Wy_hh,
    const float* __restrict__ Wx_ih, const float* __restrict__ Wy_ih,
    const float* __restrict__ bx_ih, const float* __restrict__ bx_hh,
    const float* __restrict__ by_ih, const float* __restrict__ by_hh,
    float* __restrict__ out, const float* __restrict__ P0)
{
    __shared__ half8 aH[8][128];   // ring: h(t) lives in aH[(t+1)&7], 16 KB

    const int tid  = threadIdx.x;
    const int lane = tid & 63;
    const int wv   = tid >> 6;
    const int quad = lane >> 4;
    const int l15  = lane & 15;
    const int lrow = lane & 3;

    const int bid  = blockIdx.x;   // 0..255
    const int isY  = bid >= 128;
    const int g0   = isY ? bid - 128 : bid;
    const int b    = g0 >> 5;
    const int c0   = (g0 & 31) << 2;
    const int slot = isY;

    const float* Whh  = (isY ? Wy_hh : Wx_hh) + (size_t)DI * HH * HH;
    const float* WihN = (isY ? Wy_ih : Wx_ih) + (size_t)(DI + 1) * HH * HH;
    const float* bihN = (isY ? by_ih : bx_ih) + (DI + 1) * HH;
    const float* bhhN = (isY ? by_hh : bx_hh) + (DI + 1) * HH;

    const int n_0 = (wv << 5) + l15;
    const int n_1 = n_0 + 16;

    half8 Bhh0[8], Bhh1[8], BN0[8], BN1[8];
    {
        const float* h0p = Whh  + (size_t)n_0 * HH;
        const float* h1p = Whh  + (size_t)n_1 * HH;
        const float* i0p = WihN + (size_t)n_0 * HH;
        const float* i1p = WihN + (size_t)n_1 * HH;
#pragma unroll
        for (int f = 0; f < 8; ++f) {
            const int k = (f << 5) + (quad << 3);
            Bhh0[f] = ldfrag_f32(h0p, k);
            Bhh1[f] = ldfrag_f32(h1p, k);
            BN0[f]  = ldfrag_f32(i0p, k);
            BN1[f]  = ldfrag_f32(i1p, k);
        }
    }
    const float biasN0 = bihN[n_0] + bhhN[n_0];
    const float biasN1 = bihN[n_1] + bhhN[n_1];

    // ---- P read FIFO (2 scalars/step, 4-deep)
    float pA[4], pB[4];
    int rj = isY ? 0 : ((c0 + quad) & 127);
    const float* rp;
    if constexpr (DI == 0) {
        rp = P0 + (size_t)isY * 131072 + (size_t)b * 128 * HH;
    } else {
        rp = out + (isY ? ((size_t)(b * SS + c0 + quad) * TT)
                        : ((size_t)b * SS * TT + rj)) * 2 * HH
                 + (size_t)slot * HH;
    }
    auto rbump = [&]() {
        if constexpr (DI == 0) { rp += HH; }
        else if (isY)          { rp += 2 * HH; }
        else { rp += (size_t)(rj == 127 ? 1 : 129) * 2 * HH; rj = (rj + 1) & 127; }
    };
#pragma unroll
    for (int u = 0; u < 4; ++u) { pA[u] = rp[n_0]; pB[u] = rp[n_1]; rbump(); }

    // ---- P_next store: group first-cell t4; lane quad = step, reg r = chain
    auto store_group = [&](int t4, const float4v& v0, const float4v& v1) {
        const int t = t4 + quad;
#pragma unroll
        for (int r = 0; r < 4; ++r) {
            const int ch = c0 + r;
            const size_t cell = isY ? ((size_t)(b * SS + ch) * TT + t)
                                    : ((size_t)(b * SS + t) * TT + ((ch + t) & 127));
            float* p = out + cell * 2 * HH + (size_t)slot * HH;
            p[n_0] = v0[r];
            p[n_1] = v1[r];
        }
    };

    if (tid < 128) {
        half8 z;
#pragma unroll
        for (int e = 0; e < 8; ++e) z[e] = (_Float16)0.f;
        aH[0][tid] = z;   // h(-1) = 0
    }
    __syncthreads();

    const int hi  = l15 >> 3;
    const int lo3 = l15 & 7;
    const int ihe = (quad << 2) + (l15 & 3);

    float4v pn0 = {0.f, 0.f, 0.f, 0.f}, pn1 = {0.f, 0.f, 0.f, 0.f};
    float4v st0 = {0.f, 0.f, 0.f, 0.f}, st1 = {0.f, 0.f, 0.f, 0.f};

    for (int g = 0; g < 32; ++g) {
#pragma unroll
        for (int u = 0; u < 4; ++u) {
            const int s = (g << 2) + u;

            // ---- EARLY ih frag reads (R14): issue at top of step so the
            // read latency hides under hh reads + MFMAs; consumed post-scatter.
            half8 ihr0, ihr1;
            if (g >= 1) {
                const half8* ib = aH[((g << 2) - 3 + (l15 >> 2)) & 7];
                const int f0 = (u << 1);
                ihr0 = ib[(f0 << 4) + ihe];
                ihr1 = ib[((f0 + 1) << 4) + ihe];
            }

            // hh frags: h(s-1) from aH[s&7]; rows mirror mod 4
            const half8* hb = aH[s & 7];
            half8 ahr[8];
#pragma unroll
            for (int f = 0; f < 8; ++f)
                ahr[f] = hb[(f << 4) + (quad << 2) + lrow];

            // ---- post-barrier: deferred store of group g-2 ----
            if (u == 0 && g >= 2) store_group(((g - 2) << 2), st0, st1);

            // FIFO: consume P(s), refill slot u with P(s+4)
            const float pAu = pA[u], pBu = pB[u];
            if (s + 4 < 128) { pA[u] = rp[n_0]; pB[u] = rp[n_1]; rbump(); }

            // hh MFMAs, K split into 2 halves (4-deep dep chains)
            float4v a0a = {0.f,0.f,0.f,0.f}, a0b = {0.f,0.f,0.f,0.f};
            float4v a1a = {0.f,0.f,0.f,0.f}, a1b = {0.f,0.f,0.f,0.f};
            __builtin_amdgcn_s_setprio(1);
#pragma unroll
            for (int f = 0; f < 4; ++f) {
                a0a = __builtin_amdgcn_mfma_f32_16x16x32_f16(ahr[f],     Bhh0[f],     a0a, 0, 0, 0);
                a1a = __builtin_amdgcn_mfma_f32_16x16x32_f16(ahr[f],     Bhh1[f],     a1a, 0, 0, 0);
                a0b = __builtin_amdgcn_mfma_f32_16x16x32_f16(ahr[f + 4], Bhh0[f + 4], a0b, 0, 0, 0);
                a1b = __builtin_amdgcn_mfma_f32_16x16x32_f16(ahr[f + 4], Bhh1[f + 4], a1b, 0, 0, 0);
            }
            __builtin_amdgcn_s_setprio(0);

            // h(s) = tanh(hh + P(s)); scatter into aH[(s+1)&7]
            const float h0 = fast_tanh(sel4(a0a, quad) + sel4(a0b, quad) + pAu);
            const float h1 = fast_tanh(sel4(a1a, quad) + sel4(a1b, quad) + pBu);
            unsigned short* aHu = (unsigned short*)aH[(s + 1) & 7];
            aHu[(((wv << 4) + (hi << 2) + quad) << 3) + lo3]       = f2hbits(h0);
            aHu[(((wv << 4) + ((2 + hi) << 2) + quad) << 3) + lo3] = f2hbits(h1);

            __builtin_amdgcn_sched_barrier(0);

            // ---- batched ih for group g-1: 4 MFMA, operands pre-read ----
            if (g >= 1) {
                if (u == 0) {
                    pn0 = float4v{biasN0, biasN0, biasN0, biasN0};
                    pn1 = float4v{biasN1, biasN1, biasN1, biasN1};
                }
                const int f0 = (u << 1);
                pn0 = __builtin_amdgcn_mfma_f32_16x16x32_f16(ihr0, BN0[f0],     pn0, 0, 0, 0);
                pn1 = __builtin_amdgcn_mfma_f32_16x16x32_f16(ihr0, BN1[f0],     pn1, 0, 0, 0);
                pn0 = __builtin_amdgcn_mfma_f32_16x16x32_f16(ihr1, BN0[f0 + 1], pn0, 0, 0, 0);
                pn1 = __builtin_amdgcn_mfma_f32_16x16x32_f16(ihr1, BN1[f0 + 1], pn1, 0, 0, 0);
                if (u == 3) { st0 = pn0; st1 = pn1; }
            }

            lds_barrier();                       // LDS-only: no vmcnt drain
            __builtin_amdgcn_sched_barrier(0);
        }
    }

    // epilogue: store group 30 (carried), compute+store group 31
    store_group((30 << 2), st0, st1);
    {
        float4v p0 = {biasN0, biasN0, biasN0, biasN0};
        float4v p1 = {biasN1, biasN1, biasN1, biasN1};
        const half8* ib = aH[(5 + (l15 >> 2)) & 7];   // h(124..127) -> bufs 5,6,7,0
#pragma unroll
        for (int f = 0; f < 8; ++f) {
            const half8 af = ib[(f << 4) + ihe];
            p0 = __builtin_amdgcn_mfma_f32_16x16x32_f16(af, BN0[f], p0, 0, 0, 0);
            p1 = __builtin_amdgcn_mfma_f32_16x16x32_f16(af, BN1[f], p1, 0, 0, 0);
        }
        store_group((31 << 2), p0, p1);
    }
}

extern "C" __global__ void __launch_bounds__(512, 1)
grid_rnn2f_d0(const float* __restrict__ Wx_hh, const float* __restrict__ Wy_hh,
              const float* __restrict__ Wx_ih, const float* __restrict__ Wy_ih,
              const float* __restrict__ bx_ih, const float* __restrict__ bx_hh,
              const float* __restrict__ by_ih, const float* __restrict__ by_hh,
              float* __restrict__ out, const float* __restrict__ P0)
{ rnn2f_body<0>(Wx_hh, Wy_hh, Wx_ih, Wy_ih, bx_ih, bx_hh, by_ih, by_hh, out, P0); }

extern "C" __global__ void __launch_bounds__(512, 1)
grid_rnn2f_d1(const float* __restrict__ Wx_hh, const float* __restrict__ Wy_hh,
              const float* __restrict__ Wx_ih, const float* __restrict__ Wy_ih,
              const float* __restrict__ bx_ih, const float* __restrict__ bx_hh,
              const float* __restrict__ by_ih, const float* __restrict__ by_hh,
              float* __restrict__ out, const float* __restrict__ P0)
{ rnn2f_body<1>(Wx_hh, Wy_hh, Wx_ih, Wy_ih, bx_ih, bx_hh, by_ih, by_hh, out, P0); }

// ===================== final depth (d=2): h -> out =====================
extern "C" __global__ void __launch_bounds__(512, 2)
grid_rnn2_last(const float* __restrict__ Wx_hh, const float* __restrict__ Wy_hh,
               float* __restrict__ out)
{
    __shared__ half8 aH[2][128];

    const int tid  = threadIdx.x;
    const int lane = tid & 63;
    const int wv   = tid >> 6;
    const int quad = lane >> 4;
    const int l15  = lane & 15;
    const int lrow = lane & 3;

    const int bid  = blockIdx.x;
    const int isY  = bid >= 128;
    const int g    = isY ? bid - 128 : bid;
    const int b    = g >> 5;
    const int c0   = (g & 31) << 2;
    const int slot = isY;

    const float* Whh = (isY ? Wy_hh : Wx_hh) + (size_t)2 * HH * HH;

    const int n_0 = (wv << 5) + l15;
    const int n_1 = n_0 + 16;

    half8 Bhh0[8], Bhh1[8];
    {
        const float* r0 = Whh + (size_t)n_0 * HH;
        const float* r1 = Whh + (size_t)n_1 * HH;
#pragma unroll
        for (int f = 0; f < 8; ++f) {
            const int k = (f << 5) + (quad << 3);
            Bhh0[f] = ldfrag_f32(r0, k);
            Bhh1[f] = ldfrag_f32(r1, k);
        }
    }

    // ---- P read FIFO (chain = quad, 4-deep)
    float pA[4], pB[4];
    int rj = isY ? 0 : ((c0 + quad) & 127);
    const float* rp = out + (isY ? ((size_t)(b * SS + c0 + quad) * TT)
                                 : ((size_t)b * SS * TT + rj)) * 2 * HH
                          + (size_t)slot * HH;
    auto rbump = [&]() {
        if (isY) { rp += 2 * HH; }
        else { rp += (size_t)(rj == 127 ? 1 : 129) * 2 * HH; rj = (rj + 1) & 127; }
    };
#pragma unroll
    for (int u = 0; u < 4; ++u) { pA[u] = rp[n_0]; pB[u] = rp[n_1]; rbump(); }

    // ---- spread h-store: thread handles chain sm=tid>>7, floats kk,kk+1
    const int sm = tid >> 7;
    const int kk = (tid & 127) << 1;
    int sj = isY ? 0 : ((c0 + sm) & 127);
    float* sp = out + (isY ? ((size_t)(b * SS + c0 + sm) * TT)
                           : ((size_t)b * SS * TT + sj)) * 2 * HH
                    + (size_t)slot * HH + kk;
    const int rb32 = ((((kk >> 3) << 2) + sm) << 3 | (kk & 7)) >> 1;  // u32 idx in aH buf

    auto store_spread = [&](int bufi) {
        const unsigned int* a32 = (const unsigned int*)aH[bufi];
        const unsigned int w = a32[rb32];
        const _Float16 lo = __builtin_bit_cast(_Float16, (unsigned short)(w & 0xffff));
        const _Float16 hv = __builtin_bit_cast(_Float16, (unsigned short)(w >> 16));
        float2v t; t[0] = (float)lo; t[1] = (float)hv;
        *(float2v*)sp = t;
        if (isY) { sp += 2 * HH; }
        else { sp += (size_t)(sj == 127 ? 1 : 129) * 2 * HH; sj = (sj + 1) & 127; }
    };

    if (tid < 128) {
        half8 z;
#pragma unroll
        for (int e = 0; e < 8; ++e) z[e] = (_Float16)0.f;
        aH[0][tid] = z;
    }
    __syncthreads();

    const int hi  = l15 >> 3;
    const int lo3 = l15 & 7;

    int buf = 0;
    for (int s4 = 0; s4 < 128; s4 += 4) {
#pragma unroll
        for (int u = 0; u < 4; ++u) {
            const int s = s4 + u;

            if (s > 0) store_spread(buf);   // h(s-1) -> out (overwrites consumed P)

            const float pAu = pA[u], pBu = pB[u];
            if (s + 4 < 128) { pA[u] = rp[n_0]; pB[u] = rp[n_1]; rbump(); }

            half8 ahr[8];
#pragma unroll
            for (int f = 0; f < 8; ++f)
                ahr[f] = aH[buf][(f << 4) + (quad << 2) + lrow];

            float4v a0a = {0.f,0.f,0.f,0.f}, a0b = {0.f,0.f,0.f,0.f};
            float4v a1a = {0.f,0.f,0.f,0.f}, a1b = {0.f,0.f,0.f,0.f};
            __builtin_amdgcn_s_setprio(1);
#pragma unroll
            for (int f = 0; f < 4; ++f) {
                a0a = __builtin_amdgcn_mfma_f32_16x16x32_f16(ahr[f],     Bhh0[f],     a0a, 0, 0, 0);
                a1a = __builtin_amdgcn_mfma_f32_16x16x32_f16(ahr[f],     Bhh1[f],     a1a, 0, 0, 0);
                a0b = __builtin_amdgcn_mfma_f32_16x16x32_f16(ahr[f + 4], Bhh0[f + 4], a0b, 0, 0, 0);
                a1b = __builtin_amdgcn_mfma_f32_16x16x32_f16(ahr[f + 4], Bhh1[f + 4], a1b, 0, 0, 0);
            }
            __builtin_amdgcn_s_setprio(0);

            const float h0 = fast_tanh(sel4(a0a, quad) + sel4(a0b, quad) + pAu);
            const float h1 = fast_tanh(sel4(a1a, quad) + sel4(a1b, quad) + pBu);
            unsigned short* aHu = (unsigned short*)aH[buf ^ 1];
            aHu[(((wv << 4) + (hi << 2) + quad) << 3) + lo3]       = f2hbits(h0);
            aHu[(((wv << 4) + ((2 + hi) << 2) + quad) << 3) + lo3] = f2hbits(h1);

            lds_barrier();
            __builtin_amdgcn_sched_barrier(0);
            buf ^= 1;
        }
    }

    store_spread(buf);   // h(127)
}

// ===================== fallback (tiny ws): v1 monolithic path ===============
template <int DI>
__device__ __forceinline__ void grid_rnn_body_v1(
    const float* __restrict__ src, const float* __restrict__ trg,
    const float* __restrict__ Wx_ih, const float* __restrict__ Wx_hh,
    const float* __restrict__ bx_ih, const float* __restrict__ bx_hh,
    const float* __restrict__ Wy_ih, const float* __restrict__ Wy_hh,
    const float* __restrict__ by_ih, const float* __restrict__ by_hh,
    float* __restrict__ out)
{
    __shared__ half8 aX[2][128];
    __shared__ half8 aH[2][128];

    const int tid  = threadIdx.x;
    const int lane = tid & 63;
    const int wv   = tid >> 6;
    const int quad = lane >> 4;
    const int l15  = lane & 15;

    const int bid  = blockIdx.x;
    const int isY  = bid >= 128;
    const int g    = isY ? bid - 128 : bid;
    const int b    = g >> 5;
    const int c0   = (g & 31) << 2;
    const int slot = isY;

    const float* Wih = (isY ? Wy_ih : Wx_ih) + (size_t)DI * HH * HH;
    const float* Whh = (isY ? Wy_hh : Wx_hh) + (size_t)DI * HH * HH;
    const float* bih = (isY ? by_ih : bx_ih) + DI * HH;
    const float* bhh = (isY ? by_hh : bx_hh) + DI * HH;

    const int n_0 = (wv << 5) + l15;
    const int n_1 = n_0 + 16;

    half8 Bih0[8], Bih1[8], Bhh0[8], Bhh1[8];
    {
        const float* r0i = Wih + (size_t)n_0 * HH;
        const float* r1i = Wih + (size_t)n_1 * HH;
        const float* r0h = Whh + (size_t)n_0 * HH;
        const float* r1h = Whh + (size_t)n_1 * HH;
#pragma unroll
        for (int f = 0; f < 8; ++f) {
            const int k = (f << 5) + (quad << 3);
            Bih0[f] = ldfrag_f32(r0i, k);
            Bih1[f] = ldfrag_f32(r1i, k);
            Bhh0[f] = ldfrag_f32(r0h, k);
            Bhh1[f] = ldfrag_f32(r1h, k);
        }
    }
    const float bias0 = bih[n_0] + bhh[n_0];
    const float bias1 = bih[n_1] + bhh[n_1];

    const int sact = (tid < 128);
    const int cm   = tid & 3;
    const int ck0  = (tid >> 2) << 3;
    const int chc  = c0 + cm;

    auto stage_now = [&](int sn) -> half8 {
        const int i = isY ? chc : sn;
        const int j = isY ? sn : ((chc + sn) & 127);
        const size_t cell = (size_t)(b * SS + i) * TT + j;
        half8 v;
        if constexpr (DI == 0) {
            const float* row = isY ? (trg + (size_t)(b * TT + j) * HH)
                                   : (src + (size_t)(b * SS + i) * HH);
            const float4v u0 = *(const float4v*)(row + ck0);
            const float4v u1 = *(const float4v*)(row + ck0 + 4);
#pragma unroll
            for (int e = 0; e < 4; ++e) { v[e] = (_Float16)u0[e]; v[4 + e] = (_Float16)u1[e]; }
        } else {
            const float* row = out + cell * 2 * HH + (size_t)slot * HH + ck0;
            const float4v u0 = *(const float4v*)(row);
            const float4v u1 = *(const float4v*)(row + 4);
#pragma unroll
            for (int e = 0; e < 4; ++e) { v[e] = (_Float16)u0[e]; v[4 + e] = (_Float16)u1[e]; }
        }
        return v;
    };

    auto store_h = [&](int sp, int bufi) {
        const half8 v = aH[bufi][tid];
        const int i = isY ? chc : sp;
        const int j = isY ? sp : ((chc + sp) & 127);
        const size_t cell = (size_t)(b * SS + i) * TT + j;
        float* p = out + cell * 2 * HH + (size_t)slot * HH + ck0;
        float4v u0, u1;
#pragma unroll
        for (int e = 0; e < 4; ++e) { u0[e] = (float)v[e]; u1[e] = (float)v[4 + e]; }
        *(float4v*)p = u0;
        *(float4v*)(p + 4) = u1;
    };

    if (sact) {
        half8 z;
#pragma unroll
        for (int e = 0; e < 8; ++e) z[e] = (_Float16)0.f;
        aH[0][tid] = z;
        aX[0][tid] = stage_now(0);
    }
    __syncthreads();

    const int lrow = lane & 3;

    int buf = 0;
    for (int s = 0; s < 128; ++s) {
        if (s > 0 && sact) store_h(s - 1, buf);
        if (sact) {
            int t = s + 1; if (t > 127) t = 127;
            aX[buf ^ 1][tid] = stage_now(t);
        }

        half8 axr[8], ahr[8];
#pragma unroll
        for (int f = 0; f < 8; ++f) {
            const int e = (f << 4) + (quad << 2) + lrow;
            axr[f] = aX[buf][e];
            ahr[f] = aH[buf][e];
        }

        float4v ax0 = {bias0, bias0, bias0, bias0};
        float4v ax1 = {bias1, bias1, bias1, bias1};
        float4v ah0 = {0.f, 0.f, 0.f, 0.f};
        float4v ah1 = {0.f, 0.f, 0.f, 0.f};
#pragma unroll
        for (int f = 0; f < 8; ++f) {
            ax0 = __builtin_amdgcn_mfma_f32_16x16x32_f16(axr[f], Bih0[f], ax0, 0, 0, 0);
            ax1 = __builtin_amdgcn_mfma_f32_16x16x32_f16(axr[f], Bih1[f], ax1, 0, 0, 0);
            ah0 = __builtin_amdgcn_mfma_f32_16x16x32_f16(ahr[f], Bhh0[f], ah0, 0, 0, 0);
            ah1 = __builtin_amdgcn_mfma_f32_16x16x32_f16(ahr[f], Bhh1[f], ah1, 0, 0, 0);
        }

        if (quad == 0) {
            unsigned short* aHu = (unsigned short*)aH[buf ^ 1];
            const int lo3 = lane & 7;
            const int hi  = lane >> 3;
#pragma unroll
            for (int r = 0; r < 4; ++r) {
                const float h0 = fast_tanh(ax0[r] + ah0[r]);
                const float h1 = fast_tanh(ax1[r] + ah1[r]);
                aHu[(wv << 7) + (hi << 5) + (r << 3) + lo3]       = f2hbits(h0);
                aHu[(wv << 7) + ((2 + hi) << 5) + (r << 3) + lo3] = f2hbits(h1);
            }
        }

        lds_barrier();
        buf ^= 1;
    }

    if (sact) store_h(127, buf);
}

extern "C" __global__ void __launch_bounds__(512, 2)
grid_rnn_v1_d0(const float* __restrict__ src, const float* __restrict__ trg,
               const float* __restrict__ Wx_ih, const float* __restrict__ Wx_hh,
               const float* __restrict__ bx_ih, const float* __restrict__ bx_hh,
               const float* __restrict__ Wy_ih, const float* __restrict__ Wy_hh,
               const float* __restrict__ by_ih, const float* __restrict__ by_hh,
               float* __restrict__ out)
{ grid_rnn_body_v1<0>(src, trg, Wx_ih, Wx_hh, bx_ih, bx_hh, Wy_ih, Wy_hh, by_ih, by_hh, out); }

extern "C" __global__ void __launch_bounds__(512, 2)
grid_rnn_v1_d1(const float* __restrict__ src, const float* __restrict__ trg,
               const float* __restrict__ Wx_ih, const float* __restrict__ Wx_hh,
               const float* __restrict__ bx_ih, const float* __restrict__ bx_hh,
               const float* __restrict__ Wy_ih, const float* __restrict__ Wy_hh,
               const float* __restrict__ by_ih, const float* __restrict__ by_hh,
               float* __restrict__ out)
{ grid_rnn_body_v1<1>(src, trg, Wx_ih, Wx_hh, bx_ih, bx_hh, Wy_ih, Wy_hh, by_ih, by_hh, out); }

extern "C" __global__ void __launch_bounds__(512, 2)
grid_rnn_v1_d2(const float* __restrict__ src, const float* __restrict__ trg,
               const float* __restrict__ Wx_ih, const float* __restrict__ Wx_hh,
               const float* __restrict__ bx_ih, const float* __restrict__ bx_hh,
               const float* __restrict__ Wy_ih, const float* __restrict__ Wy_hh,
               const float* __restrict__ by_ih, const float* __restrict__ by_hh,
               float* __restrict__ out)
{ grid_rnn_body_v1<2>(src, trg, Wx_ih, Wx_hh, bx_ih, bx_hh, Wy_ih, Wy_hh, by_ih, by_hh, out); }

// ===================== launch =====================
extern "C" void kernel_launch(void* const* d_in, const int* in_sizes, int n_in,
                              void* d_out, int out_size, void* d_ws, size_t ws_size,
                              hipStream_t stream) {
    const float* src   = (const float*)d_in[0];
    const float* trg   = (const float*)d_in[1];
    const float* Wx_ih = (const float*)d_in[2];
    const float* Wx_hh = (const float*)d_in[3];
    const float* bx_ih = (const float*)d_in[4];
    const float* bx_hh = (const float*)d_in[5];
    const float* Wy_ih = (const float*)d_in[6];
    const float* Wy_hh = (const float*)d_in[7];
    const float* by_ih = (const float*)d_in[8];
    const float* by_hh = (const float*)d_in[9];
    float* out = (float*)d_out;
    float* wsf = (float*)d_ws;

    const size_t needP0 = (size_t)2 * 131072 * sizeof(float);  // 1 MB

    if (ws_size >= needP0) {
        hipLaunchKernelGGL(grid_gemm0, dim3(16), dim3(512), 0, stream,
                           src, trg, Wx_ih, Wy_ih, bx_ih, bx_hh, by_ih, by_hh, wsf);
        hipLaunchKernelGGL(grid_rnn2f_d0, dim3(256), dim3(512), 0, stream,
                           Wx_hh, Wy_hh, Wx_ih, Wy_ih, bx_ih, bx_hh, by_ih, by_hh,
                           out, (const float*)wsf);
        hipLaunchKernelGGL(grid_rnn2f_d1, dim3(256), dim3(512), 0, stream,
                           Wx_hh, Wy_hh, Wx_ih, Wy_ih, bx_ih, bx_hh, by_ih, by_hh,
                           out, (const float*)wsf);
        hipLaunchKernelGGL(grid_rnn2_last, dim3(256), dim3(512), 0, stream,
                           Wx_hh, Wy_hh, out);
    } else {
        hipLaunchKernelGGL(grid_rnn_v1_d0, dim3(256), dim3(512), 0, stream,
                           src, trg, Wx_ih, Wx_hh, bx_ih, bx_hh,
                           Wy_ih, Wy_hh, by_ih, by_hh, out);
        hipLaunchKernelGGL(grid_rnn_v1_d1, dim3(256), dim3(512), 0, stream,
                           src, trg, Wx_ih, Wx_hh, bx_ih, bx_hh,
                           Wy_ih, Wy_hh, by_ih, by_hh, out);
        hipLaunchKernelGGL(grid_rnn_v1_d2, dim3(256), dim3(512), 0, stream,
                           src, trg, Wx_ih, Wx_hh, bx_ih, bx_hh,
                           Wy_ih, Wy_hh, by_ih, by_hh, out);
    }
}

// Round 10
// 418.149 us; speedup vs baseline: 1.6287x; 1.0588x over previous
//
#include <hip/hip_runtime.h>

// GridRNN B=4, S=T=128, H=256, D=3 — R15: exact revert to R11 (best: 418us).
//
// Session evidence for this configuration being the local optimum:
//   R12 (8-slot unroll, const-folded):   -27us  (scratch spill: +10MB FETCH/+19MB WRITE)
//   R13 (cooperative 4-phase fusion):   -263us  (grid.sync ~80us each on MI355X)
//   R14 (ih-read hoist to step top):     -24us  (spill again: +15MB WRITE; in-order
//                                                LDS returns delay hh frags)
// Law learned: extending register live ranges across the 16-MFMA hh block
// converts directly into scratch spill; the 4-deep FIFO + runtime ring
// indices + ih-after-scatter schedule is spill-free at VGPR=128.
//
// Pipeline (ws >= 1MB path; ws holds compact P0, f32, 1 MB):
//   gemm0      : P0[dir][b*128+t][n] = x0 @ Wih[0]^T + bih0+bhh0 -> ws
//   rnn2f<0>   : h=tanh(P0 + h@Whh[0]^T); batched h x Wih[1] -> P1 -> out
//   rnn2f<1>   : h=tanh(P1 + h@Whh[1]^T); batched h x Wih[2] -> P2 -> out
//   rnn2_last  : h=tanh(P2 + h@Whh[2]^T); h -> out f32 (spread store)
//
// rnn2f structure:
//  - aH ring 8-deep: h(t) in aH[(t+1)&7]; hh of step s reads aH[s&7].
//  - ih for group g-1 batched over group g's 4 steps (16 real rows =
//    4 chains x 4 steps): 2 frag reads + 4 MFMA per step, post-scatter.
//  - hh accumulators split into K=128 halves (4-deep dep chains).
//  - LDS-only barrier (lgkmcnt+s_barrier): stores retire lazily, FIFO
//    loads stay in flight across steps.

#define SS 128
#define TT 128
#define HH 256
#define GRID_ELEMS ((size_t)4 * 128 * 128 * 256)

typedef _Float16 half8 __attribute__((ext_vector_type(8)));
typedef float float4v __attribute__((ext_vector_type(4)));
typedef float float2v __attribute__((ext_vector_type(2)));

__device__ __forceinline__ float fast_tanh(float x) {
    float e = __expf(2.0f * x);
    return 1.0f - 2.0f / (e + 1.0f);
}

__device__ __forceinline__ unsigned short f2hbits(float x) {
    _Float16 h = (_Float16)x;
    return __builtin_bit_cast(unsigned short, h);
}

__device__ __forceinline__ float sel4(float4v v, int q) {
    float a = (q & 1) ? v[1] : v[0];
    float b = (q & 1) ? v[3] : v[2];
    return (q & 2) ? b : a;
}

__device__ __forceinline__ void lds_barrier() {
    asm volatile("s_waitcnt lgkmcnt(0)" ::: "memory");
    __builtin_amdgcn_s_barrier();
}

__device__ __forceinline__ half8 ldfrag_f32(const float* rowp, int k) {
    const float4v u0 = *(const float4v*)(rowp + k);
    const float4v u1 = *(const float4v*)(rowp + k + 4);
    half8 v;
#pragma unroll
    for (int e = 0; e < 4; ++e) { v[e] = (_Float16)u0[e]; v[4 + e] = (_Float16)u1[e]; }
    return v;
}

// ===================== gemm0: compact P0 -> ws =====================
extern "C" __global__ void __launch_bounds__(512, 2)
grid_gemm0(const float* __restrict__ src, const float* __restrict__ trg,
           const float* __restrict__ Wx_ih, const float* __restrict__ Wy_ih,
           const float* __restrict__ bx_ih, const float* __restrict__ bx_hh,
           const float* __restrict__ by_ih, const float* __restrict__ by_hh,
           float* __restrict__ P0)
{
    __shared__ half8 aT[2048];   // 64 rows x 256 k

    const int tid  = threadIdx.x;
    const int lane = tid & 63;
    const int wv   = tid >> 6;
    const int quad = lane >> 4;
    const int l15  = lane & 15;

    const int bx    = blockIdx.x;   // 0..15
    const int dir   = bx >> 3;
    const int mtile = bx & 7;

    const float* Wih = dir ? Wy_ih : Wx_ih;   // depth 0
    const float* bih = dir ? by_ih : bx_ih;
    const float* bhh = dir ? by_hh : bx_hh;

    const int n_0 = (wv << 5) + l15;
    const int n_1 = n_0 + 16;

    half8 B0[8], B1[8];
    {
        const float* r0 = Wih + (size_t)n_0 * HH;
        const float* r1 = Wih + (size_t)n_1 * HH;
#pragma unroll
        for (int f = 0; f < 8; ++f) {
            const int k = (f << 5) + (quad << 3);
            B0[f] = ldfrag_f32(r0, k);
            B1[f] = ldfrag_f32(r1, k);
        }
    }
    const float bias0 = bih[n_0] + bhh[n_0];
    const float bias1 = bih[n_1] + bhh[n_1];

#pragma unroll
    for (int i = 0; i < 4; ++i) {
        const int c  = (tid << 2) + i;
        const int r  = c >> 5;
        const int kc = c & 31;
        const int R  = (mtile << 6) + r;
        const int b  = R >> 7, ii = R & 127;
        const float* row = (dir ? trg : src) + (size_t)((b << 7) + ii) * HH + (kc << 3);
        const float4v u0 = *(const float4v*)(row);
        const float4v u1 = *(const float4v*)(row + 4);
        half8 v;
#pragma unroll
        for (int e = 0; e < 4; ++e) { v[e] = (_Float16)u0[e]; v[4 + e] = (_Float16)u1[e]; }
        aT[((r >> 4) << 9) + ((kc >> 2) << 6) + ((kc & 3) << 4) + (r & 15)] = v;
    }
    __syncthreads();

#pragma unroll
    for (int msub = 0; msub < 4; ++msub) {
        half8 af[8];
#pragma unroll
        for (int f = 0; f < 8; ++f)
            af[f] = aT[(msub << 9) + (f << 6) + (quad << 4) + l15];

        float4v c0 = {bias0, bias0, bias0, bias0};
        float4v c1 = {bias1, bias1, bias1, bias1};
#pragma unroll
        for (int f = 0; f < 8; ++f) {
            c0 = __builtin_amdgcn_mfma_f32_16x16x32_f16(af[f], B0[f], c0, 0, 0, 0);
            c1 = __builtin_amdgcn_mfma_f32_16x16x32_f16(af[f], B1[f], c1, 0, 0, 0);
        }
#pragma unroll
        for (int r = 0; r < 4; ++r) {
            const int row = (msub << 4) + (quad << 2) + r;
            float* p = P0 + (size_t)dir * 131072 + (size_t)((mtile << 6) + row) * HH;
            p[n_0] = c0[r];
            p[n_1] = c1[r];
        }
    }
}

// ===================== fused recurrence (depths 0,1) =====================
template <int DI>
__device__ __forceinline__ void rnn2f_body(
    const float* __restrict__ Wx_hh, const float* __restrict__ Wy_hh,
    const float* __restrict__ Wx_ih, const float* __restrict__ Wy_ih,
    const float* __restrict__ bx_ih, const float* __restrict__ bx_hh,
    const float* __restrict__ by_ih, const float* __restrict__ by_hh,
    float* __restrict__ out, const float* __restrict__ P0)
{
    __shared__ half8 aH[8][128];   // ring: h(t) lives in aH[(t+1)&7], 16 KB

    const int tid  = threadIdx.x;
    const int lane = tid & 63;
    const int wv   = tid >> 6;
    const int quad = lane >> 4;
    const int l15  = lane & 15;
    const int lrow = lane & 3;

    const int bid  = blockIdx.x;   // 0..255
    const int isY  = bid >= 128;
    const int g0   = isY ? bid - 128 : bid;
    const int b    = g0 >> 5;
    const int c0   = (g0 & 31) << 2;
    const int slot = isY;

    const float* Whh  = (isY ? Wy_hh : Wx_hh) + (size_t)DI * HH * HH;
    const float* WihN = (isY ? Wy_ih : Wx_ih) + (size_t)(DI + 1) * HH * HH;
    const float* bihN = (isY ? by_ih : bx_ih) + (DI + 1) * HH;
    const float* bhhN = (isY ? by_hh : bx_hh) + (DI + 1) * HH;

    const int n_0 = (wv << 5) + l15;
    const int n_1 = n_0 + 16;

    half8 Bhh0[8], Bhh1[8], BN0[8], BN1[8];
    {
        const float* h0p = Whh  + (size_t)n_0 * HH;
        const float* h1p = Whh  + (size_t)n_1 * HH;
        const float* i0p = WihN + (size_t)n_0 * HH;
        const float* i1p = WihN + (size_t)n_1 * HH;
#pragma unroll
        for (int f = 0; f < 8; ++f) {
            const int k = (f << 5) + (quad << 3);
            Bhh0[f] = ldfrag_f32(h0p, k);
            Bhh1[f] = ldfrag_f32(h1p, k);
            BN0[f]  = ldfrag_f32(i0p, k);
            BN1[f]  = ldfrag_f32(i1p, k);
        }
    }
    const float biasN0 = bihN[n_0] + bhhN[n_0];
    const float biasN1 = bihN[n_1] + bhhN[n_1];

    // ---- P read FIFO (2 scalars/step, 4-deep)
    float pA[4], pB[4];
    int rj = isY ? 0 : ((c0 + quad) & 127);
    const float* rp;
    if constexpr (DI == 0) {
        rp = P0 + (size_t)isY * 131072 + (size_t)b * 128 * HH;
    } else {
        rp = out + (isY ? ((size_t)(b * SS + c0 + quad) * TT)
                        : ((size_t)b * SS * TT + rj)) * 2 * HH
                 + (size_t)slot * HH;
    }
    auto rbump = [&]() {
        if constexpr (DI == 0) { rp += HH; }
        else if (isY)          { rp += 2 * HH; }
        else { rp += (size_t)(rj == 127 ? 1 : 129) * 2 * HH; rj = (rj + 1) & 127; }
    };
#pragma unroll
    for (int u = 0; u < 4; ++u) { pA[u] = rp[n_0]; pB[u] = rp[n_1]; rbump(); }

    // ---- P_next store: group first-cell t4; lane quad = step, reg r = chain
    auto store_group = [&](int t4, const float4v& v0, const float4v& v1) {
        const int t = t4 + quad;
#pragma unroll
        for (int r = 0; r < 4; ++r) {
            const int ch = c0 + r;
            const size_t cell = isY ? ((size_t)(b * SS + ch) * TT + t)
                                    : ((size_t)(b * SS + t) * TT + ((ch + t) & 127));
            float* p = out + cell * 2 * HH + (size_t)slot * HH;
            p[n_0] = v0[r];
            p[n_1] = v1[r];
        }
    };

    if (tid < 128) {
        half8 z;
#pragma unroll
        for (int e = 0; e < 8; ++e) z[e] = (_Float16)0.f;
        aH[0][tid] = z;   // h(-1) = 0
    }
    __syncthreads();

    const int hi  = l15 >> 3;
    const int lo3 = l15 & 7;

    float4v pn0 = {0.f, 0.f, 0.f, 0.f}, pn1 = {0.f, 0.f, 0.f, 0.f};
    float4v st0 = {0.f, 0.f, 0.f, 0.f}, st1 = {0.f, 0.f, 0.f, 0.f};

    for (int g = 0; g < 32; ++g) {
#pragma unroll
        for (int u = 0; u < 4; ++u) {
            const int s = (g << 2) + u;

            // ---- post-barrier: deferred store of group g-2 ----
            if (u == 0 && g >= 2) store_group(((g - 2) << 2), st0, st1);

            // FIFO: consume P(s), refill slot u with P(s+4)
            const float pAu = pA[u], pBu = pB[u];
            if (s + 4 < 128) { pA[u] = rp[n_0]; pB[u] = rp[n_1]; rbump(); }

            // hh frags: h(s-1) from aH[s&7]; rows mirror mod 4
            const half8* hb = aH[s & 7];
            half8 ahr[8];
#pragma unroll
            for (int f = 0; f < 8; ++f)
                ahr[f] = hb[(f << 4) + (quad << 2) + lrow];

            // hh MFMAs, K split into 2 halves (4-deep dep chains)
            float4v a0a = {0.f,0.f,0.f,0.f}, a0b = {0.f,0.f,0.f,0.f};
            float4v a1a = {0.f,0.f,0.f,0.f}, a1b = {0.f,0.f,0.f,0.f};
            __builtin_amdgcn_s_setprio(1);
#pragma unroll
            for (int f = 0; f < 4; ++f) {
                a0a = __builtin_amdgcn_mfma_f32_16x16x32_f16(ahr[f],     Bhh0[f],     a0a, 0, 0, 0);
                a1a = __builtin_amdgcn_mfma_f32_16x16x32_f16(ahr[f],     Bhh1[f],     a1a, 0, 0, 0);
                a0b = __builtin_amdgcn_mfma_f32_16x16x32_f16(ahr[f + 4], Bhh0[f + 4], a0b, 0, 0, 0);
                a1b = __builtin_amdgcn_mfma_f32_16x16x32_f16(ahr[f + 4], Bhh1[f + 4], a1b, 0, 0, 0);
            }
            __builtin_amdgcn_s_setprio(0);

            // h(s) = tanh(hh + P(s)); scatter into aH[(s+1)&7]
            const float h0 = fast_tanh(sel4(a0a, quad) + sel4(a0b, quad) + pAu);
            const float h1 = fast_tanh(sel4(a1a, quad) + sel4(a1b, quad) + pBu);
            unsigned short* aHu = (unsigned short*)aH[(s + 1) & 7];
            aHu[(((wv << 4) + (hi << 2) + quad) << 3) + lo3]       = f2hbits(h0);
            aHu[(((wv << 4) + ((2 + hi) << 2) + quad) << 3) + lo3] = f2hbits(h1);

            __builtin_amdgcn_sched_barrier(0);

            // ---- batched ih for group g-1: 2 frag reads + 4 MFMA ----
            if (g >= 1) {
                if (u == 0) {
                    pn0 = float4v{biasN0, biasN0, biasN0, biasN0};
                    pn1 = float4v{biasN1, biasN1, biasN1, biasN1};
                }
                const half8* ib = aH[((g << 2) - 3 + (l15 >> 2)) & 7];
#pragma unroll
                for (int ff = 0; ff < 2; ++ff) {
                    const int f = (u << 1) + ff;
                    const half8 af = ib[(f << 4) + (quad << 2) + (l15 & 3)];
                    pn0 = __builtin_amdgcn_mfma_f32_16x16x32_f16(af, BN0[f], pn0, 0, 0, 0);
                    pn1 = __builtin_amdgcn_mfma_f32_16x16x32_f16(af, BN1[f], pn1, 0, 0, 0);
                }
                if (u == 3) { st0 = pn0; st1 = pn1; }
            }

            lds_barrier();                       // LDS-only: no vmcnt drain
            __builtin_amdgcn_sched_barrier(0);
        }
    }

    // epilogue: store group 30 (carried), compute+store group 31
    store_group((30 << 2), st0, st1);
    {
        float4v p0 = {biasN0, biasN0, biasN0, biasN0};
        float4v p1 = {biasN1, biasN1, biasN1, biasN1};
        const half8* ib = aH[(5 + (l15 >> 2)) & 7];   // h(124..127) -> bufs 5,6,7,0
#pragma unroll
        for (int f = 0; f < 8; ++f) {
            const half8 af = ib[(f << 4) + (quad << 2) + (l15 & 3)];
            p0 = __builtin_amdgcn_mfma_f32_16x16x32_f16(af, BN0[f], p0, 0, 0, 0);
            p1 = __builtin_amdgcn_mfma_f32_16x16x32_f16(af, BN1[f], p1, 0, 0, 0);
        }
        store_group((31 << 2), p0, p1);
    }
}

extern "C" __global__ void __launch_bounds__(512, 1)
grid_rnn2f_d0(const float* __restrict__ Wx_hh, const float* __restrict__ Wy_hh,
              const float* __restrict__ Wx_ih, const float* __restrict__ Wy_ih,
              const float* __restrict__ bx_ih, const float* __restrict__ bx_hh,
              const float* __restrict__ by_ih, const float* __restrict__ by_hh,
              float* __restrict__ out, const float* __restrict__ P0)
{ rnn2f_body<0>(Wx_hh, Wy_hh, Wx_ih, Wy_ih, bx_ih, bx_hh, by_ih, by_hh, out, P0); }

extern "C" __global__ void __launch_bounds__(512, 1)
grid_rnn2f_d1(const float* __restrict__ Wx_hh, const float* __restrict__ Wy_hh,
              const float* __restrict__ Wx_ih, const float* __restrict__ Wy_ih,
              const float* __restrict__ bx_ih, const float* __restrict__ bx_hh,
              const float* __restrict__ by_ih, const float* __restrict__ by_hh,
              float* __restrict__ out, const float* __restrict__ P0)
{ rnn2f_body<1>(Wx_hh, Wy_hh, Wx_ih, Wy_ih, bx_ih, bx_hh, by_ih, by_hh, out, P0); }

// ===================== final depth (d=2): h -> out =====================
extern "C" __global__ void __launch_bounds__(512, 2)
grid_rnn2_last(const float* __restrict__ Wx_hh, const float* __restrict__ Wy_hh,
               float* __restrict__ out)
{
    __shared__ half8 aH[2][128];

    const int tid  = threadIdx.x;
    const int lane = tid & 63;
    const int wv   = tid >> 6;
    const int quad = lane >> 4;
    const int l15  = lane & 15;
    const int lrow = lane & 3;

    const int bid  = blockIdx.x;
    const int isY  = bid >= 128;
    const int g    = isY ? bid - 128 : bid;
    const int b    = g >> 5;
    const int c0   = (g & 31) << 2;
    const int slot = isY;

    const float* Whh = (isY ? Wy_hh : Wx_hh) + (size_t)2 * HH * HH;

    const int n_0 = (wv << 5) + l15;
    const int n_1 = n_0 + 16;

    half8 Bhh0[8], Bhh1[8];
    {
        const float* r0 = Whh + (size_t)n_0 * HH;
        const float* r1 = Whh + (size_t)n_1 * HH;
#pragma unroll
        for (int f = 0; f < 8; ++f) {
            const int k = (f << 5) + (quad << 3);
            Bhh0[f] = ldfrag_f32(r0, k);
            Bhh1[f] = ldfrag_f32(r1, k);
        }
    }

    // ---- P read FIFO (chain = quad, 4-deep)
    float pA[4], pB[4];
    int rj = isY ? 0 : ((c0 + quad) & 127);
    const float* rp = out + (isY ? ((size_t)(b * SS + c0 + quad) * TT)
                                 : ((size_t)b * SS * TT + rj)) * 2 * HH
                          + (size_t)slot * HH;
    auto rbump = [&]() {
        if (isY) { rp += 2 * HH; }
        else { rp += (size_t)(rj == 127 ? 1 : 129) * 2 * HH; rj = (rj + 1) & 127; }
    };
#pragma unroll
    for (int u = 0; u < 4; ++u) { pA[u] = rp[n_0]; pB[u] = rp[n_1]; rbump(); }

    // ---- spread h-store: thread handles chain sm=tid>>7, floats kk,kk+1
    const int sm = tid >> 7;
    const int kk = (tid & 127) << 1;
    int sj = isY ? 0 : ((c0 + sm) & 127);
    float* sp = out + (isY ? ((size_t)(b * SS + c0 + sm) * TT)
                           : ((size_t)b * SS * TT + sj)) * 2 * HH
                    + (size_t)slot * HH + kk;
    const int rb32 = ((((kk >> 3) << 2) + sm) << 3 | (kk & 7)) >> 1;  // u32 idx in aH buf

    auto store_spread = [&](int bufi) {
        const unsigned int* a32 = (const unsigned int*)aH[bufi];
        const unsigned int w = a32[rb32];
        const _Float16 lo = __builtin_bit_cast(_Float16, (unsigned short)(w & 0xffff));
        const _Float16 hv = __builtin_bit_cast(_Float16, (unsigned short)(w >> 16));
        float2v t; t[0] = (float)lo; t[1] = (float)hv;
        *(float2v*)sp = t;
        if (isY) { sp += 2 * HH; }
        else { sp += (size_t)(sj == 127 ? 1 : 129) * 2 * HH; sj = (sj + 1) & 127; }
    };

    if (tid < 128) {
        half8 z;
#pragma unroll
        for (int e = 0; e < 8; ++e) z[e] = (_Float16)0.f;
        aH[0][tid] = z;
    }
    __syncthreads();

    const int hi  = l15 >> 3;
    const int lo3 = l15 & 7;

    int buf = 0;
    for (int s4 = 0; s4 < 128; s4 += 4) {
#pragma unroll
        for (int u = 0; u < 4; ++u) {
            const int s = s4 + u;

            if (s > 0) store_spread(buf);   // h(s-1) -> out (overwrites consumed P)

            const float pAu = pA[u], pBu = pB[u];
            if (s + 4 < 128) { pA[u] = rp[n_0]; pB[u] = rp[n_1]; rbump(); }

            half8 ahr[8];
#pragma unroll
            for (int f = 0; f < 8; ++f)
                ahr[f] = aH[buf][(f << 4) + (quad << 2) + lrow];

            float4v a0a = {0.f,0.f,0.f,0.f}, a0b = {0.f,0.f,0.f,0.f};
            float4v a1a = {0.f,0.f,0.f,0.f}, a1b = {0.f,0.f,0.f,0.f};
            __builtin_amdgcn_s_setprio(1);
#pragma unroll
            for (int f = 0; f < 4; ++f) {
                a0a = __builtin_amdgcn_mfma_f32_16x16x32_f16(ahr[f],     Bhh0[f],     a0a, 0, 0, 0);
                a1a = __builtin_amdgcn_mfma_f32_16x16x32_f16(ahr[f],     Bhh1[f],     a1a, 0, 0, 0);
                a0b = __builtin_amdgcn_mfma_f32_16x16x32_f16(ahr[f + 4], Bhh0[f + 4], a0b, 0, 0, 0);
                a1b = __builtin_amdgcn_mfma_f32_16x16x32_f16(ahr[f + 4], Bhh1[f + 4], a1b, 0, 0, 0);
            }
            __builtin_amdgcn_s_setprio(0);

            const float h0 = fast_tanh(sel4(a0a, quad) + sel4(a0b, quad) + pAu);
            const float h1 = fast_tanh(sel4(a1a, quad) + sel4(a1b, quad) + pBu);
            unsigned short* aHu = (unsigned short*)aH[buf ^ 1];
            aHu[(((wv << 4) + (hi << 2) + quad) << 3) + lo3]       = f2hbits(h0);
            aHu[(((wv << 4) + ((2 + hi) << 2) + quad) << 3) + lo3] = f2hbits(h1);

            lds_barrier();
            __builtin_amdgcn_sched_barrier(0);
            buf ^= 1;
        }
    }

    store_spread(buf);   // h(127)
}

// ===================== fallback (tiny ws): v1 monolithic path ===============
template <int DI>
__device__ __forceinline__ void grid_rnn_body_v1(
    const float* __restrict__ src, const float* __restrict__ trg,
    const float* __restrict__ Wx_ih, const float* __restrict__ Wx_hh,
    const float* __restrict__ bx_ih, const float* __restrict__ bx_hh,
    const float* __restrict__ Wy_ih, const float* __restrict__ Wy_hh,
    const float* __restrict__ by_ih, const float* __restrict__ by_hh,
    float* __restrict__ out)
{
    __shared__ half8 aX[2][128];
    __shared__ half8 aH[2][128];

    const int tid  = threadIdx.x;
    const int lane = tid & 63;
    const int wv   = tid >> 6;
    const int quad = lane >> 4;
    const int l15  = lane & 15;

    const int bid  = blockIdx.x;
    const int isY  = bid >= 128;
    const int g    = isY ? bid - 128 : bid;
    const int b    = g >> 5;
    const int c0   = (g & 31) << 2;
    const int slot = isY;

    const float* Wih = (isY ? Wy_ih : Wx_ih) + (size_t)DI * HH * HH;
    const float* Whh = (isY ? Wy_hh : Wx_hh) + (size_t)DI * HH * HH;
    const float* bih = (isY ? by_ih : bx_ih) + DI * HH;
    const float* bhh = (isY ? by_hh : bx_hh) + DI * HH;

    const int n_0 = (wv << 5) + l15;
    const int n_1 = n_0 + 16;

    half8 Bih0[8], Bih1[8], Bhh0[8], Bhh1[8];
    {
        const float* r0i = Wih + (size_t)n_0 * HH;
        const float* r1i = Wih + (size_t)n_1 * HH;
        const float* r0h = Whh + (size_t)n_0 * HH;
        const float* r1h = Whh + (size_t)n_1 * HH;
#pragma unroll
        for (int f = 0; f < 8; ++f) {
            const int k = (f << 5) + (quad << 3);
            Bih0[f] = ldfrag_f32(r0i, k);
            Bih1[f] = ldfrag_f32(r1i, k);
            Bhh0[f] = ldfrag_f32(r0h, k);
            Bhh1[f] = ldfrag_f32(r1h, k);
        }
    }
    const float bias0 = bih[n_0] + bhh[n_0];
    const float bias1 = bih[n_1] + bhh[n_1];

    const int sact = (tid < 128);
    const int cm   = tid & 3;
    const int ck0  = (tid >> 2) << 3;
    const int chc  = c0 + cm;

    auto stage_now = [&](int sn) -> half8 {
        const int i = isY ? chc : sn;
        const int j = isY ? sn : ((chc + sn) & 127);
        const size_t cell = (size_t)(b * SS + i) * TT + j;
        half8 v;
        if constexpr (DI == 0) {
            const float* row = isY ? (trg + (size_t)(b * TT + j) * HH)
                                   : (src + (size_t)(b * SS + i) * HH);
            const float4v u0 = *(const float4v*)(row + ck0);
            const float4v u1 = *(const float4v*)(row + ck0 + 4);
#pragma unroll
            for (int e = 0; e < 4; ++e) { v[e] = (_Float16)u0[e]; v[4 + e] = (_Float16)u1[e]; }
        } else {
            const float* row = out + cell * 2 * HH + (size_t)slot * HH + ck0;
            const float4v u0 = *(const float4v*)(row);
            const float4v u1 = *(const float4v*)(row + 4);
#pragma unroll
            for (int e = 0; e < 4; ++e) { v[e] = (_Float16)u0[e]; v[4 + e] = (_Float16)u1[e]; }
        }
        return v;
    };

    auto store_h = [&](int sp, int bufi) {
        const half8 v = aH[bufi][tid];
        const int i = isY ? chc : sp;
        const int j = isY ? sp : ((chc + sp) & 127);
        const size_t cell = (size_t)(b * SS + i) * TT + j;
        float* p = out + cell * 2 * HH + (size_t)slot * HH + ck0;
        float4v u0, u1;
#pragma unroll
        for (int e = 0; e < 4; ++e) { u0[e] = (float)v[e]; u1[e] = (float)v[4 + e]; }
        *(float4v*)p = u0;
        *(float4v*)(p + 4) = u1;
    };

    if (sact) {
        half8 z;
#pragma unroll
        for (int e = 0; e < 8; ++e) z[e] = (_Float16)0.f;
        aH[0][tid] = z;
        aX[0][tid] = stage_now(0);
    }
    __syncthreads();

    const int lrow = lane & 3;

    int buf = 0;
    for (int s = 0; s < 128; ++s) {
        if (s > 0 && sact) store_h(s - 1, buf);
        if (sact) {
            int t = s + 1; if (t > 127) t = 127;
            aX[buf ^ 1][tid] = stage_now(t);
        }

        half8 axr[8], ahr[8];
#pragma unroll
        for (int f = 0; f < 8; ++f) {
            const int e = (f << 4) + (quad << 2) + lrow;
            axr[f] = aX[buf][e];
            ahr[f] = aH[buf][e];
        }

        float4v ax0 = {bias0, bias0, bias0, bias0};
        float4v ax1 = {bias1, bias1, bias1, bias1};
        float4v ah0 = {0.f, 0.f, 0.f, 0.f};
        float4v ah1 = {0.f, 0.f, 0.f, 0.f};
#pragma unroll
        for (int f = 0; f < 8; ++f) {
            ax0 = __builtin_amdgcn_mfma_f32_16x16x32_f16(axr[f], Bih0[f], ax0, 0, 0, 0);
            ax1 = __builtin_amdgcn_mfma_f32_16x16x32_f16(axr[f], Bih1[f], ax1, 0, 0, 0);
            ah0 = __builtin_amdgcn_mfma_f32_16x16x32_f16(ahr[f], Bhh0[f], ah0, 0, 0, 0);
            ah1 = __builtin_amdgcn_mfma_f32_16x16x32_f16(ahr[f], Bhh1[f], ah1, 0, 0, 0);
        }

        if (quad == 0) {
            unsigned short* aHu = (unsigned short*)aH[buf ^ 1];
            const int lo3 = lane & 7;
            const int hi  = lane >> 3;
#pragma unroll
            for (int r = 0; r < 4; ++r) {
                const float h0 = fast_tanh(ax0[r] + ah0[r]);
                const float h1 = fast_tanh(ax1[r] + ah1[r]);
                aHu[(wv << 7) + (hi << 5) + (r << 3) + lo3]       = f2hbits(h0);
                aHu[(wv << 7) + ((2 + hi) << 5) + (r << 3) + lo3] = f2hbits(h1);
            }
        }

        lds_barrier();
        buf ^= 1;
    }

    if (sact) store_h(127, buf);
}

extern "C" __global__ void __launch_bounds__(512, 2)
grid_rnn_v1_d0(const float* __restrict__ src, const float* __restrict__ trg,
               const float* __restrict__ Wx_ih, const float* __restrict__ Wx_hh,
               const float* __restrict__ bx_ih, const float* __restrict__ bx_hh,
               const float* __restrict__ Wy_ih, const float* __restrict__ Wy_hh,
               const float* __restrict__ by_ih, const float* __restrict__ by_hh,
               float* __restrict__ out)
{ grid_rnn_body_v1<0>(src, trg, Wx_ih, Wx_hh, bx_ih, bx_hh, Wy_ih, Wy_hh, by_ih, by_hh, out); }

extern "C" __global__ void __launch_bounds__(512, 2)
grid_rnn_v1_d1(const float* __restrict__ src, const float* __restrict__ trg,
               const float* __restrict__ Wx_ih, const float* __restrict__ Wx_hh,
               const float* __restrict__ bx_ih, const float* __restrict__ bx_hh,
               const float* __restrict__ Wy_ih, const float* __restrict__ Wy_hh,
               const float* __restrict__ by_ih, const float* __restrict__ by_hh,
               float* __restrict__ out)
{ grid_rnn_body_v1<1>(src, trg, Wx_ih, Wx_hh, bx_ih, bx_hh, Wy_ih, Wy_hh, by_ih, by_hh, out); }

extern "C" __global__ void __launch_bounds__(512, 2)
grid_rnn_v1_d2(const float* __restrict__ src, const float* __restrict__ trg,
               const float* __restrict__ Wx_ih, const float* __restrict__ Wx_hh,
               const float* __restrict__ bx_ih, const float* __restrict__ bx_hh,
               const float* __restrict__ Wy_ih, const float* __restrict__ Wy_hh,
               const float* __restrict__ by_ih, const float* __restrict__ by_hh,
               float* __restrict__ out)
{ grid_rnn_body_v1<2>(src, trg, Wx_ih, Wx_hh, bx_ih, bx_hh, Wy_ih, Wy_hh, by_ih, by_hh, out); }

// ===================== launch =====================
extern "C" void kernel_launch(void* const* d_in, const int* in_sizes, int n_in,
                              void* d_out, int out_size, void* d_ws, size_t ws_size,
                              hipStream_t stream) {
    const float* src   = (const float*)d_in[0];
    const float* trg   = (const float*)d_in[1];
    const float* Wx_ih = (const float*)d_in[2];
    const float* Wx_hh = (const float*)d_in[3];
    const float* bx_ih = (const float*)d_in[4];
    const float* bx_hh = (const float*)d_in[5];
    const float* Wy_ih = (const float*)d_in[6];
    const float* Wy_hh = (const float*)d_in[7];
    const float* by_ih = (const float*)d_in[8];
    const float* by_hh = (const float*)d_in[9];
    float* out = (float*)d_out;
    float* wsf = (float*)d_ws;

    const size_t needP0 = (size_t)2 * 131072 * sizeof(float);  // 1 MB

    if (ws_size >= needP0) {
        hipLaunchKernelGGL(grid_gemm0, dim3(16), dim3(512), 0, stream,
                           src, trg, Wx_ih, Wy_ih, bx_ih, bx_hh, by_ih, by_hh, wsf);
        hipLaunchKernelGGL(grid_rnn2f_d0, dim3(256), dim3(512), 0, stream,
                           Wx_hh, Wy_hh, Wx_ih, Wy_ih, bx_ih, bx_hh, by_ih, by_hh,
                           out, (const float*)wsf);
        hipLaunchKernelGGL(grid_rnn2f_d1, dim3(256), dim3(512), 0, stream,
                           Wx_hh, Wy_hh, Wx_ih, Wy_ih, bx_ih, bx_hh, by_ih, by_hh,
                           out, (const float*)wsf);
        hipLaunchKernelGGL(grid_rnn2_last, dim3(256), dim3(512), 0, stream,
                           Wx_hh, Wy_hh, out);
    } else {
        hipLaunchKernelGGL(grid_rnn_v1_d0, dim3(256), dim3(512), 0, stream,
                           src, trg, Wx_ih, Wx_hh, bx_ih, bx_hh,
                           Wy_ih, Wy_hh, by_ih, by_hh, out);
        hipLaunchKernelGGL(grid_rnn_v1_d1, dim3(256), dim3(512), 0, stream,
                           src, trg, Wx_ih, Wx_hh, bx_ih, bx_hh,
                           Wy_ih, Wy_hh, by_ih, by_hh, out);
        hipLaunchKernelGGL(grid_rnn_v1_d2, dim3(256), dim3(512), 0, stream,
                           src, trg, Wx_ih, Wx_hh, bx_ih, bx_hh,
                           Wy_ih, Wy_hh, by_ih, by_hh, out);
    }
}